// Round 1
// baseline (1565.944 us; speedup 1.0000x reference)
//
#include <hip/hip_runtime.h>
#include <hip/hip_bf16.h>
#include <math.h>

#define D_MODEL 1024
#define D_STATE 16
#define D_CONV  4
#define DT_RANK 64
#define D_INNER 2048
#define BATCH   2
#define SEQ     1024
#define BT      (BATCH*SEQ)   // 2048 rows total

// ---------------------------------------------------------------------------
// Generic fp32 GEMM: C[m][n] = sum_k A[m*lda+k] * B[n*ldb+k]   ("NT" layout:
// both A and B rows contiguous in K). Tiles staged K-major in LDS (+1 pad).
// EPI: 0 = plain store, 1 = softplus(acc + bias[n]) (for the dt projection).
// ---------------------------------------------------------------------------
template<int BM, int BN, int BK, int TM, int TN, int EPI>
__launch_bounds__(256)
__global__ void gemm_nt(const float* __restrict__ A, int lda,
                        const float* __restrict__ B, int ldb,
                        float* __restrict__ C, int ldc,
                        int K, const float* __restrict__ bias) {
    constexpr int BX = BN / TN;          // threads along n
    constexpr int BY = BM / TM;          // threads along m
    constexpr int THREADS = BX * BY;

    __shared__ float As[BK][BM + 1];
    __shared__ float Bs[BK][BN + 1];

    const int tid = threadIdx.x;
    const int tx  = tid % BX;
    const int ty  = tid / BX;
    const int m0  = blockIdx.y * BM;
    const int n0  = blockIdx.x * BN;

    float acc[TM][TN] = {};

    for (int k0 = 0; k0 < K; k0 += BK) {
        // stage A tile (BM x BK) as As[k][m]
        #pragma unroll
        for (int l = 0; l < (BM * BK) / (THREADS * 4); ++l) {
            int idx = (tid + l * THREADS) * 4;
            int row = idx / BK, col = idx % BK;
            const float4 v = *reinterpret_cast<const float4*>(
                &A[(size_t)(m0 + row) * lda + k0 + col]);
            As[col + 0][row] = v.x; As[col + 1][row] = v.y;
            As[col + 2][row] = v.z; As[col + 3][row] = v.w;
        }
        // stage B tile (BN x BK) as Bs[k][n]
        #pragma unroll
        for (int l = 0; l < (BN * BK) / (THREADS * 4); ++l) {
            int idx = (tid + l * THREADS) * 4;
            int row = idx / BK, col = idx % BK;
            const float4 v = *reinterpret_cast<const float4*>(
                &B[(size_t)(n0 + row) * ldb + k0 + col]);
            Bs[col + 0][row] = v.x; Bs[col + 1][row] = v.y;
            Bs[col + 2][row] = v.z; Bs[col + 3][row] = v.w;
        }
        __syncthreads();

        #pragma unroll
        for (int kk = 0; kk < BK; ++kk) {
            float a[TM], b[TN];
            #pragma unroll
            for (int i = 0; i < TM; ++i) a[i] = As[kk][ty * TM + i];
            #pragma unroll
            for (int j = 0; j < TN; ++j) b[j] = Bs[kk][tx * TN + j];
            #pragma unroll
            for (int i = 0; i < TM; ++i)
                #pragma unroll
                for (int j = 0; j < TN; ++j)
                    acc[i][j] = fmaf(a[i], b[j], acc[i][j]);
        }
        __syncthreads();
    }

    // epilogue + store (TN == 4 assumed for float4 store)
    #pragma unroll
    for (int i = 0; i < TM; ++i) {
        float* outp = &C[(size_t)(m0 + ty * TM + i) * ldc + n0 + tx * TN];
        float4 v;
        float vals[4];
        #pragma unroll
        for (int j = 0; j < TN; ++j) {
            float val = acc[i][j];
            if (EPI == 1) {
                val += bias[n0 + tx * TN + j];
                val = (val > 20.f) ? val : log1pf(expf(val));  // softplus
            }
            vals[j] = val;
        }
        v.x = vals[0]; v.y = vals[1]; v.z = vals[2]; v.w = vals[3];
        *reinterpret_cast<float4*>(outp) = v;
    }
}

// ---------------------------------------------------------------------------
// Depthwise causal conv (width 4, left pad 3) + bias + SiLU.
// x_in, x_act layout: [BT][D_INNER] (channel contiguous).
// ---------------------------------------------------------------------------
__global__ void conv_silu_kernel(const float* __restrict__ x_in,
                                 const float* __restrict__ w,
                                 const float* __restrict__ b,
                                 float* __restrict__ x_act) {
    const int idx = blockIdx.x * blockDim.x + threadIdx.x;  // over BT*D_INNER
    const int ch = idx % D_INNER;
    const int m  = idx / D_INNER;       // b*SEQ + t
    const int t  = m % SEQ;

    float acc = b[ch];
    #pragma unroll
    for (int j = 0; j < D_CONV; ++j) {
        int tt = t - (D_CONV - 1) + j;
        if (tt >= 0)
            acc = fmaf(w[ch * D_CONV + j], x_in[(size_t)(m - (D_CONV - 1) + j) * D_INNER + ch], acc);
    }
    x_act[idx] = acc / (1.f + expf(-acc));  // SiLU
}

// ---------------------------------------------------------------------------
// Selective scan + skip (u*D) + gate with silu(z).
// 16 lanes per (batch, channel): lane s owns state s. yf may alias z.
// ---------------------------------------------------------------------------
__global__ void scan_kernel(const float* __restrict__ x_act,
                            const float* __restrict__ dt,
                            const float* __restrict__ dbc,
                            const float* __restrict__ A_log,
                            const float* __restrict__ Dp,
                            const float* z,          // NOT restrict: aliases yf
                            float* yf) {
    const int lane = threadIdx.x & 15;
    const int grp  = threadIdx.x >> 4;               // 0..15 channel-groups/block
    const int d    = blockIdx.x * 16 + grp;
    const int b    = blockIdx.y;

    const float Av = -expf(A_log[d * D_STATE + lane]);
    const float Dv = Dp[d];
    float h = 0.f;

    const int mbase = b * SEQ;
    for (int t = 0; t < SEQ; ++t) {
        const int m = mbase + t;
        const float dtv = dt[(size_t)m * D_INNER + d];
        const float u   = x_act[(size_t)m * D_INNER + d];
        const float Bv  = dbc[(size_t)m * 96 + DT_RANK + lane];
        const float Cv  = dbc[(size_t)m * 96 + DT_RANK + D_STATE + lane];

        h = fmaf(expf(dtv * Av), h, dtv * Bv * u);
        float p = h * Cv;
        #pragma unroll
        for (int off = 8; off; off >>= 1) p += __shfl_xor(p, off, 16);

        if (lane == 0) {
            const float yv = p + u * Dv;
            const float zv = z[(size_t)m * D_INNER + d];
            yf[(size_t)m * D_INNER + d] = yv * (zv / (1.f + expf(-zv)));
        }
    }
}

// ---------------------------------------------------------------------------
extern "C" void kernel_launch(void* const* d_in, const int* in_sizes, int n_in,
                              void* d_out, int out_size, void* d_ws, size_t ws_size,
                              hipStream_t stream) {
    const float* x      = (const float*)d_in[0];
    const float* W_in   = (const float*)d_in[1];
    const float* conv_w = (const float*)d_in[2];
    const float* conv_b = (const float*)d_in[3];
    const float* W_x    = (const float*)d_in[4];
    const float* W_dt   = (const float*)d_in[5];
    const float* b_dt   = (const float*)d_in[6];
    const float* A_log  = (const float*)d_in[7];
    const float* Dp     = (const float*)d_in[8];
    const float* W_out  = (const float*)d_in[9];
    float* out = (float*)d_out;

    // workspace layout (floats); dt reuses x_in, yf reuses z
    float* ws    = (float*)d_ws;
    float* x_in  = ws;                                 // BT*D_INNER
    float* z     = x_in  + (size_t)BT * D_INNER;       // BT*D_INNER
    float* x_act = z     + (size_t)BT * D_INNER;       // BT*D_INNER
    float* dbc   = x_act + (size_t)BT * D_INNER;       // BT*96
    float* dtbuf = x_in;   // x_in dead after conv
    float* yf    = z;      // z consumed (and overwritten in-place) by scan

    // 1) in_proj: xz = x @ W_in^T  (split into x_in / z halves)
    gemm_nt<64,64,16,4,4,0><<<dim3(D_INNER/64, BT/64), 256, 0, stream>>>(
        x, D_MODEL, W_in, D_MODEL, x_in, D_INNER, D_MODEL, nullptr);
    gemm_nt<64,64,16,4,4,0><<<dim3(D_INNER/64, BT/64), 256, 0, stream>>>(
        x, D_MODEL, W_in + (size_t)D_INNER * D_MODEL, D_MODEL, z, D_INNER, D_MODEL, nullptr);

    // 2) depthwise causal conv + SiLU
    conv_silu_kernel<<<dim3((BT * D_INNER) / 256), 256, 0, stream>>>(
        x_in, conv_w, conv_b, x_act);

    // 3) dbc = x_act @ W_x^T   [BT][96]
    gemm_nt<64,32,16,4,4,0><<<dim3(96/32, BT/64), 128, 0, stream>>>(
        x_act, D_INNER, W_x, D_INNER, dbc, 96, D_INNER, nullptr);

    // 4) dt = softplus(dbc[:, :64] @ W_dt^T + b_dt)   [BT][D_INNER]
    gemm_nt<64,64,16,4,4,1><<<dim3(D_INNER/64, BT/64), 256, 0, stream>>>(
        dbc, 96, W_dt, DT_RANK, dtbuf, D_INNER, DT_RANK, b_dt);

    // 5) selective scan + skip + gate
    scan_kernel<<<dim3(D_INNER/16, BATCH), 256, 0, stream>>>(
        x_act, dtbuf, dbc, A_log, Dp, z, yf);

    // 6) out_proj: out = yf @ W_out^T
    gemm_nt<64,64,16,4,4,0><<<dim3(D_MODEL/64, BT/64), 256, 0, stream>>>(
        yf, D_INNER, W_out, D_INNER, out, D_MODEL, D_INNER, nullptr);
}

// Round 2
// 857.030 us; speedup vs baseline: 1.8272x; 1.8272x over previous
//
#include <hip/hip_runtime.h>
#include <hip/hip_bf16.h>
#include <math.h>

#define D_MODEL 1024
#define D_STATE 16
#define D_CONV  4
#define DT_RANK 64
#define D_INNER 2048
#define BATCH   2
#define SEQ     1024
#define BT      (BATCH*SEQ)   // 2048 rows total
#define NCHUNK  16
#define CLEN    (SEQ/NCHUNK)  // 64

// ---------------------------------------------------------------------------
// Generic fp32 GEMM: C[m][n] = sum_k A[m*lda+k] * B[n*ldb+k]   ("NT" layout).
// EPI: 0 = plain store, 1 = softplus(acc + bias[n]) (dt projection).
// ---------------------------------------------------------------------------
template<int BM, int BN, int BK, int TM, int TN, int EPI>
__launch_bounds__(256)
__global__ void gemm_nt(const float* __restrict__ A, int lda,
                        const float* __restrict__ B, int ldb,
                        float* __restrict__ C, int ldc,
                        int K, const float* __restrict__ bias) {
    constexpr int BX = BN / TN;
    constexpr int BY = BM / TM;
    constexpr int THREADS = BX * BY;

    __shared__ float As[BK][BM + 1];
    __shared__ float Bs[BK][BN + 1];

    const int tid = threadIdx.x;
    const int tx  = tid % BX;
    const int ty  = tid / BX;
    const int m0  = blockIdx.y * BM;
    const int n0  = blockIdx.x * BN;

    float acc[TM][TN] = {};

    for (int k0 = 0; k0 < K; k0 += BK) {
        #pragma unroll
        for (int l = 0; l < (BM * BK) / (THREADS * 4); ++l) {
            int idx = (tid + l * THREADS) * 4;
            int row = idx / BK, col = idx % BK;
            const float4 v = *reinterpret_cast<const float4*>(
                &A[(size_t)(m0 + row) * lda + k0 + col]);
            As[col + 0][row] = v.x; As[col + 1][row] = v.y;
            As[col + 2][row] = v.z; As[col + 3][row] = v.w;
        }
        #pragma unroll
        for (int l = 0; l < (BN * BK) / (THREADS * 4); ++l) {
            int idx = (tid + l * THREADS) * 4;
            int row = idx / BK, col = idx % BK;
            const float4 v = *reinterpret_cast<const float4*>(
                &B[(size_t)(n0 + row) * ldb + k0 + col]);
            Bs[col + 0][row] = v.x; Bs[col + 1][row] = v.y;
            Bs[col + 2][row] = v.z; Bs[col + 3][row] = v.w;
        }
        __syncthreads();

        #pragma unroll
        for (int kk = 0; kk < BK; ++kk) {
            float a[TM], b[TN];
            #pragma unroll
            for (int i = 0; i < TM; ++i) a[i] = As[kk][ty * TM + i];
            #pragma unroll
            for (int j = 0; j < TN; ++j) b[j] = Bs[kk][tx * TN + j];
            #pragma unroll
            for (int i = 0; i < TM; ++i)
                #pragma unroll
                for (int j = 0; j < TN; ++j)
                    acc[i][j] = fmaf(a[i], b[j], acc[i][j]);
        }
        __syncthreads();
    }

    #pragma unroll
    for (int i = 0; i < TM; ++i) {
        float* outp = &C[(size_t)(m0 + ty * TM + i) * ldc + n0 + tx * TN];
        float vals[4];
        #pragma unroll
        for (int j = 0; j < TN; ++j) {
            float val = acc[i][j];
            if (EPI == 1) {
                val += bias[n0 + tx * TN + j];
                val = (val > 20.f) ? val : log1pf(expf(val));
            }
            vals[j] = val;
        }
        float4 v;
        v.x = vals[0]; v.y = vals[1]; v.z = vals[2]; v.w = vals[3];
        *reinterpret_cast<float4*>(outp) = v;
    }
}

// ---------------------------------------------------------------------------
// Depthwise causal conv (width 4, left pad 3) + bias + SiLU.
// ---------------------------------------------------------------------------
__global__ void conv_silu_kernel(const float* __restrict__ x_in,
                                 const float* __restrict__ w,
                                 const float* __restrict__ b,
                                 float* __restrict__ x_act) {
    const int idx = blockIdx.x * blockDim.x + threadIdx.x;
    const int ch = idx % D_INNER;
    const int m  = idx / D_INNER;
    const int t  = m % SEQ;

    float acc = b[ch];
    #pragma unroll
    for (int j = 0; j < D_CONV; ++j) {
        int tt = t - (D_CONV - 1) + j;
        if (tt >= 0)
            acc = fmaf(w[ch * D_CONV + j], x_in[(size_t)(m - (D_CONV - 1) + j) * D_INNER + ch], acc);
    }
    x_act[idx] = acc / (1.f + __expf(-acc));
}

// ---------------------------------------------------------------------------
// Chunked selective scan.
// h_t = exp(dt*A)*h_{t-1} + dt*B_t*u_t  is linear in h -> per-chunk summaries.
// Thread owns one (b, chunk, d): 16 states in registers, no cross-lane ops.
// P/F layout: [b][chunk][s][d]  (d contiguous -> coalesced).
// ---------------------------------------------------------------------------
__global__ void scan_part1(const float* __restrict__ dt,
                           const float* __restrict__ x_act,
                           const float* __restrict__ dbc,
                           const float* __restrict__ A_log,
                           float* __restrict__ P, float* __restrict__ F) {
    __shared__ float Bsh[CLEN][D_STATE];   // 4 KB
    const int tid = threadIdx.x;
    const int d = blockIdx.x * 256 + tid;
    const int c = blockIdx.y;
    const int b = blockIdx.z;
    const int mbase = b * SEQ + c * CLEN;

    {   // stage B rows: CLEN*16 floats, 4 per thread
        const int s = tid & 15, t0 = tid >> 4;
        #pragma unroll
        for (int q = 0; q < 4; ++q)
            Bsh[t0 + 16 * q][s] = dbc[(size_t)(mbase + t0 + 16 * q) * 96 + DT_RANK + s];
    }
    float A[16];
    #pragma unroll
    for (int q = 0; q < 4; ++q) {
        float4 v = *reinterpret_cast<const float4*>(&A_log[d * 16 + q * 4]);
        A[q*4+0] = -__expf(v.x); A[q*4+1] = -__expf(v.y);
        A[q*4+2] = -__expf(v.z); A[q*4+3] = -__expf(v.w);
    }
    __syncthreads();

    float h[16] = {};
    float Pp[16];
    #pragma unroll
    for (int s = 0; s < 16; ++s) Pp[s] = 1.f;

    for (int t = 0; t < CLEN; ++t) {
        const int m = mbase + t;
        const float dtv = dt[(size_t)m * D_INNER + d];
        const float u   = x_act[(size_t)m * D_INNER + d];
        const float du  = dtv * u;
        float Bv[16];
        #pragma unroll
        for (int q = 0; q < 4; ++q) {
            float4 v = *reinterpret_cast<const float4*>(&Bsh[t][q * 4]);
            Bv[q*4+0] = v.x; Bv[q*4+1] = v.y; Bv[q*4+2] = v.z; Bv[q*4+3] = v.w;
        }
        #pragma unroll
        for (int s = 0; s < 16; ++s) {
            const float dA = __expf(dtv * A[s]);
            Pp[s] *= dA;
            h[s] = fmaf(dA, h[s], du * Bv[s]);
        }
    }
    const size_t base = ((size_t)(b * NCHUNK + c) * 16) * D_INNER + d;
    #pragma unroll
    for (int s = 0; s < 16; ++s) {
        P[base + (size_t)s * D_INNER] = Pp[s];
        F[base + (size_t)s * D_INNER] = h[s];
    }
}

// Serial combine across chunks; writes each chunk's INITIAL state over F.
__global__ void scan_combine(const float* __restrict__ P, float* F) {
    const int idx = blockIdx.x * 256 + threadIdx.x;    // over B*16*D_INNER
    const int d  = idx % D_INNER;
    const int bs = idx / D_INNER;
    const int b  = bs >> 4, s = bs & 15;
    float G = 0.f;
    for (int c = 0; c < NCHUNK; ++c) {
        const size_t off = ((size_t)(b * NCHUNK + c) * 16 + s) * D_INNER + d;
        const float p = P[off], f = F[off];
        F[off] = G;                 // initial state for chunk c
        G = fmaf(p, G, f);
    }
}

// Re-run each chunk from its true initial state; fuse skip + silu(z) gate.
// zp and yf alias: all z reads are preloaded to registers BEFORE any store.
__global__ void scan_part2(const float* __restrict__ dt,
                           const float* __restrict__ x_act,
                           const float* __restrict__ dbc,
                           const float* __restrict__ A_log,
                           const float* __restrict__ Dp,
                           const float* __restrict__ Ginit,
                           const float* zp,      // aliases yf - no restrict
                           float* yf) {
    __shared__ float BCs[CLEN][32];   // [t][0:16]=B, [16:32]=C ; 8 KB
    const int tid = threadIdx.x;
    const int d = blockIdx.x * 256 + tid;
    const int c = blockIdx.y;
    const int b = blockIdx.z;
    const int mbase = b * SEQ + c * CLEN;

    {   // stage B+C: CLEN*32 floats, 2 float4 per thread
        const int t0 = tid >> 3;            // 0..31
        const int j  = (tid & 7) * 4;       // 0..28
        #pragma unroll
        for (int q = 0; q < 2; ++q) {
            float4 v = *reinterpret_cast<const float4*>(
                &dbc[(size_t)(mbase + t0 + 32 * q) * 96 + DT_RANK + j]);
            *reinterpret_cast<float4*>(&BCs[t0 + 32 * q][j]) = v;
        }
    }
    float A[16];
    #pragma unroll
    for (int q = 0; q < 4; ++q) {
        float4 v = *reinterpret_cast<const float4*>(&A_log[d * 16 + q * 4]);
        A[q*4+0] = -__expf(v.x); A[q*4+1] = -__expf(v.y);
        A[q*4+2] = -__expf(v.z); A[q*4+3] = -__expf(v.w);
    }
    float h[16];
    const size_t gbase = ((size_t)(b * NCHUNK + c) * 16) * D_INNER + d;
    #pragma unroll
    for (int s = 0; s < 16; ++s) h[s] = Ginit[gbase + (size_t)s * D_INNER];
    const float Dv = Dp[d];
    __syncthreads();

    // two half-chunks: preload z (32 regs) before the stores of each half
    for (int half = 0; half < 2; ++half) {
        const int tb = half * (CLEN / 2);
        float zreg[CLEN / 2];
        #pragma unroll
        for (int t = 0; t < CLEN / 2; ++t)
            zreg[t] = zp[(size_t)(mbase + tb + t) * D_INNER + d];

        for (int t = 0; t < CLEN / 2; ++t) {
            const int m = mbase + tb + t;
            const float dtv = dt[(size_t)m * D_INNER + d];
            const float u   = x_act[(size_t)m * D_INNER + d];
            const float du  = dtv * u;
            float Bv[16], Cv[16];
            #pragma unroll
            for (int q = 0; q < 4; ++q) {
                float4 vb = *reinterpret_cast<const float4*>(&BCs[tb + t][q * 4]);
                float4 vc = *reinterpret_cast<const float4*>(&BCs[tb + t][16 + q * 4]);
                Bv[q*4+0] = vb.x; Bv[q*4+1] = vb.y; Bv[q*4+2] = vb.z; Bv[q*4+3] = vb.w;
                Cv[q*4+0] = vc.x; Cv[q*4+1] = vc.y; Cv[q*4+2] = vc.z; Cv[q*4+3] = vc.w;
            }
            float y0 = 0.f, y1 = 0.f;
            #pragma unroll
            for (int s = 0; s < 16; s += 2) {
                const float dA0 = __expf(dtv * A[s]);
                const float dA1 = __expf(dtv * A[s + 1]);
                h[s]     = fmaf(dA0, h[s],     du * Bv[s]);
                h[s + 1] = fmaf(dA1, h[s + 1], du * Bv[s + 1]);
                y0 = fmaf(h[s],     Cv[s],     y0);
                y1 = fmaf(h[s + 1], Cv[s + 1], y1);
            }
            float y = y0 + y1;
            y = fmaf(u, Dv, y);
            const float zv = zreg[t];
            const float g  = zv / (1.f + __expf(-zv));
            yf[(size_t)m * D_INNER + d] = y * g;
        }
    }
}

// ---------------------------------------------------------------------------
extern "C" void kernel_launch(void* const* d_in, const int* in_sizes, int n_in,
                              void* d_out, int out_size, void* d_ws, size_t ws_size,
                              hipStream_t stream) {
    const float* x      = (const float*)d_in[0];
    const float* W_in   = (const float*)d_in[1];
    const float* conv_w = (const float*)d_in[2];
    const float* conv_b = (const float*)d_in[3];
    const float* W_x    = (const float*)d_in[4];
    const float* W_dt   = (const float*)d_in[5];
    const float* b_dt   = (const float*)d_in[6];
    const float* A_log  = (const float*)d_in[7];
    const float* Dp     = (const float*)d_in[8];
    const float* W_out  = (const float*)d_in[9];
    float* out = (float*)d_out;

    // workspace (floats): total ~59.5 MB
    float* ws    = (float*)d_ws;
    float* x_in  = ws;                                  // BT*D_INNER (dt reuses)
    float* z     = x_in  + (size_t)BT * D_INNER;        // BT*D_INNER (yf reuses)
    float* x_act = z     + (size_t)BT * D_INNER;        // BT*D_INNER
    float* dbc   = x_act + (size_t)BT * D_INNER;        // BT*96
    float* Pbuf  = dbc   + (size_t)BT * 96;             // B*NCHUNK*16*D_INNER
    float* Fbuf  = Pbuf  + (size_t)BATCH * NCHUNK * 16 * D_INNER;
    float* dtbuf = x_in;
    float* yf    = z;

    // 1) in_proj
    gemm_nt<64,64,16,4,4,0><<<dim3(D_INNER/64, BT/64), 256, 0, stream>>>(
        x, D_MODEL, W_in, D_MODEL, x_in, D_INNER, D_MODEL, nullptr);
    gemm_nt<64,64,16,4,4,0><<<dim3(D_INNER/64, BT/64), 256, 0, stream>>>(
        x, D_MODEL, W_in + (size_t)D_INNER * D_MODEL, D_MODEL, z, D_INNER, D_MODEL, nullptr);

    // 2) conv + SiLU
    conv_silu_kernel<<<dim3((BT * D_INNER) / 256), 256, 0, stream>>>(
        x_in, conv_w, conv_b, x_act);

    // 3) dbc = x_act @ W_x^T
    gemm_nt<64,32,16,4,4,0><<<dim3(96/32, BT/64), 128, 0, stream>>>(
        x_act, D_INNER, W_x, D_INNER, dbc, 96, D_INNER, nullptr);

    // 4) dt = softplus(dbc[:, :64] @ W_dt^T + b_dt)
    gemm_nt<64,64,16,4,4,1><<<dim3(D_INNER/64, BT/64), 256, 0, stream>>>(
        dbc, 96, W_dt, DT_RANK, dtbuf, D_INNER, DT_RANK, b_dt);

    // 5) chunked selective scan + skip + gate
    scan_part1<<<dim3(D_INNER/256, NCHUNK, BATCH), 256, 0, stream>>>(
        dtbuf, x_act, dbc, A_log, Pbuf, Fbuf);
    scan_combine<<<dim3((BATCH * 16 * D_INNER) / 256), 256, 0, stream>>>(
        Pbuf, Fbuf);
    scan_part2<<<dim3(D_INNER/256, NCHUNK, BATCH), 256, 0, stream>>>(
        dtbuf, x_act, dbc, A_log, Dp, Fbuf, z, yf);

    // 6) out_proj
    gemm_nt<64,64,16,4,4,0><<<dim3(D_MODEL/64, BT/64), 256, 0, stream>>>(
        yf, D_INNER, W_out, D_INNER, out, D_MODEL, D_INNER, nullptr);
}

// Round 3
// 496.862 us; speedup vs baseline: 3.1517x; 1.7249x over previous
//
#include <hip/hip_runtime.h>
#include <math.h>

#define D_MODEL 1024
#define D_STATE 16
#define D_CONV  4
#define DT_RANK 64
#define D_INNER 2048
#define BATCH   2
#define SEQ     1024
#define BT      (BATCH*SEQ)   // 2048 rows
#define NCHUNK  16
#define CLEN    (SEQ/NCHUNK)  // 64

typedef int   v4i __attribute__((ext_vector_type(4)));
typedef float v4f __attribute__((ext_vector_type(4)));
typedef unsigned short u16;

// ===========================================================================
// fp32 GEMM (kept for dbc/dt projections and as full fallback path)
// ===========================================================================
template<int BM, int BN, int BK, int TM, int TN, int EPI>
__launch_bounds__(256)
__global__ void gemm_nt(const float* __restrict__ A, int lda,
                        const float* __restrict__ B, int ldb,
                        float* __restrict__ C, int ldc,
                        int K, const float* __restrict__ bias) {
    constexpr int BX = BN / TN;
    constexpr int BY = BM / TM;
    constexpr int THREADS = BX * BY;

    __shared__ float As[BK][BM + 1];
    __shared__ float Bs[BK][BN + 1];

    const int tid = threadIdx.x;
    const int tx  = tid % BX;
    const int ty  = tid / BX;
    const int m0  = blockIdx.y * BM;
    const int n0  = blockIdx.x * BN;

    float acc[TM][TN] = {};

    for (int k0 = 0; k0 < K; k0 += BK) {
        #pragma unroll
        for (int l = 0; l < (BM * BK) / (THREADS * 4); ++l) {
            int idx = (tid + l * THREADS) * 4;
            int row = idx / BK, col = idx % BK;
            const float4 v = *reinterpret_cast<const float4*>(
                &A[(size_t)(m0 + row) * lda + k0 + col]);
            As[col + 0][row] = v.x; As[col + 1][row] = v.y;
            As[col + 2][row] = v.z; As[col + 3][row] = v.w;
        }
        #pragma unroll
        for (int l = 0; l < (BN * BK) / (THREADS * 4); ++l) {
            int idx = (tid + l * THREADS) * 4;
            int row = idx / BK, col = idx % BK;
            const float4 v = *reinterpret_cast<const float4*>(
                &B[(size_t)(n0 + row) * ldb + k0 + col]);
            Bs[col + 0][row] = v.x; Bs[col + 1][row] = v.y;
            Bs[col + 2][row] = v.z; Bs[col + 3][row] = v.w;
        }
        __syncthreads();

        #pragma unroll
        for (int kk = 0; kk < BK; ++kk) {
            float a[TM], b[TN];
            #pragma unroll
            for (int i = 0; i < TM; ++i) a[i] = As[kk][ty * TM + i];
            #pragma unroll
            for (int j = 0; j < TN; ++j) b[j] = Bs[kk][tx * TN + j];
            #pragma unroll
            for (int i = 0; i < TM; ++i)
                #pragma unroll
                for (int j = 0; j < TN; ++j)
                    acc[i][j] = fmaf(a[i], b[j], acc[i][j]);
        }
        __syncthreads();
    }

    #pragma unroll
    for (int i = 0; i < TM; ++i) {
        float* outp = &C[(size_t)(m0 + ty * TM + i) * ldc + n0 + tx * TN];
        float vals[4];
        #pragma unroll
        for (int j = 0; j < TN; ++j) {
            float val = acc[i][j];
            if (EPI == 1) {
                val += bias[n0 + tx * TN + j];
                val = (val > 20.f) ? val : log1pf(expf(val));
            }
            vals[j] = val;
        }
        float4 v;
        v.x = vals[0]; v.y = vals[1]; v.z = vals[2]; v.w = vals[3];
        *reinterpret_cast<float4*>(outp) = v;
    }
}

// ===========================================================================
// fp32 -> (bf16 hi, bf16 lo) split, RNE. 8 elems/thread.
// ===========================================================================
__device__ __forceinline__ u16 rne_bf16(float x) {
    unsigned int u = __float_as_uint(x);
    unsigned int r = u + 0x7FFFu + ((u >> 16) & 1u);
    return (u16)(r >> 16);
}

__global__ void split_kernel(const float* __restrict__ in,
                             u16* __restrict__ hi, u16* __restrict__ lo, int n) {
    const int i = (blockIdx.x * 256 + threadIdx.x) * 8;
    if (i >= n) return;
    float4 a = *reinterpret_cast<const float4*>(&in[i]);
    float4 b = *reinterpret_cast<const float4*>(&in[i + 4]);
    float xs[8] = {a.x, a.y, a.z, a.w, b.x, b.y, b.z, b.w};
    unsigned int hw[4], lw[4];
    #pragma unroll
    for (int q = 0; q < 4; ++q) {
        u16 h0 = rne_bf16(xs[2*q]);
        u16 h1 = rne_bf16(xs[2*q+1]);
        float d0 = xs[2*q]   - __uint_as_float((unsigned int)h0 << 16);
        float d1 = xs[2*q+1] - __uint_as_float((unsigned int)h1 << 16);
        u16 l0 = rne_bf16(d0);
        u16 l1 = rne_bf16(d1);
        hw[q] = (unsigned int)h0 | ((unsigned int)h1 << 16);
        lw[q] = (unsigned int)l0 | ((unsigned int)l1 << 16);
    }
    *reinterpret_cast<v4i*>(&hi[i]) = *reinterpret_cast<v4i*>(hw);
    *reinterpret_cast<v4i*>(&lo[i]) = *reinterpret_cast<v4i*>(lw);
}

// ===========================================================================
// Split-bf16 MFMA GEMM: C = (Ahi+Alo) @ (Bhi+Blo)^T, fp32 accumulate.
// 128x128 tile, 4 waves (each owns a 64x64 quadrant), BK=32.
// LDS pitch 40 ushorts (80B): ds_read_b128/ds_write_b128 conflict-free.
// ===========================================================================
#define MFMA_B16(ACC, Af, Bf) \
    asm("v_mfma_f32_16x16x32_bf16 %0, %1, %2, %0" : "+v"(ACC) : "v"(Af), "v"(Bf))

__launch_bounds__(256)
__global__ void gemm_mfma3(const u16* __restrict__ Ahi, const u16* __restrict__ Alo, int lda,
                           const u16* __restrict__ Bhi, const u16* __restrict__ Blo, int ldb,
                           float* __restrict__ C, int ldc, int K) {
    __shared__ u16 smem[4 * 128 * 40];          // 40 KB
    u16* sAh = smem;
    u16* sAl = smem + 5120;
    u16* sBh = smem + 10240;
    u16* sBl = smem + 15360;

    const int tid  = threadIdx.x;
    const int lane = tid & 63;
    const int wave = tid >> 6;
    const int wr   = wave >> 1, wc = wave & 1;
    const int m0   = blockIdx.y * 128, n0 = blockIdx.x * 128;

    // staging: chunk = row*4 + slot; thread covers chunks tid and tid+256
    const int r0 = tid >> 2, s0 = tid & 3;
    const size_t aRow0 = (size_t)(m0 + r0) * lda + s0 * 8;
    const size_t aRow1 = aRow0 + (size_t)64 * lda;
    const size_t bRow0 = (size_t)(n0 + r0) * ldb + s0 * 8;
    const size_t bRow1 = bRow0 + (size_t)64 * ldb;
    const int w0 = r0 * 40 + s0 * 8;
    const int w1 = (r0 + 64) * 40 + s0 * 8;

    // fragment offsets (verified m89/m91 mapping)
    const int fr = lane & 15;
    const int fk = (lane >> 4) * 8;
    int aOff[4], bOff[4];
    #pragma unroll
    for (int i = 0; i < 4; ++i) {
        aOff[i] = (wr * 64 + i * 16 + fr) * 40 + fk;
        bOff[i] = (wc * 64 + i * 16 + fr) * 40 + fk;
    }

    v4f acc[4][4];
    #pragma unroll
    for (int i = 0; i < 4; ++i)
        #pragma unroll
        for (int j = 0; j < 4; ++j)
            acc[i][j] = (v4f)0.f;

    for (int k0 = 0; k0 < K; k0 += 32) {
        *reinterpret_cast<v4i*>(&sAh[w0]) = *reinterpret_cast<const v4i*>(&Ahi[aRow0 + k0]);
        *reinterpret_cast<v4i*>(&sAh[w1]) = *reinterpret_cast<const v4i*>(&Ahi[aRow1 + k0]);
        *reinterpret_cast<v4i*>(&sAl[w0]) = *reinterpret_cast<const v4i*>(&Alo[aRow0 + k0]);
        *reinterpret_cast<v4i*>(&sAl[w1]) = *reinterpret_cast<const v4i*>(&Alo[aRow1 + k0]);
        *reinterpret_cast<v4i*>(&sBh[w0]) = *reinterpret_cast<const v4i*>(&Bhi[bRow0 + k0]);
        *reinterpret_cast<v4i*>(&sBh[w1]) = *reinterpret_cast<const v4i*>(&Bhi[bRow1 + k0]);
        *reinterpret_cast<v4i*>(&sBl[w0]) = *reinterpret_cast<const v4i*>(&Blo[bRow0 + k0]);
        *reinterpret_cast<v4i*>(&sBl[w1]) = *reinterpret_cast<const v4i*>(&Blo[bRow1 + k0]);
        __syncthreads();

        v4i ah[4], al[4], bh[4], bl[4];
        #pragma unroll
        for (int i = 0; i < 4; ++i) {
            ah[i] = *reinterpret_cast<const v4i*>(&sAh[aOff[i]]);
            al[i] = *reinterpret_cast<const v4i*>(&sAl[aOff[i]]);
            bh[i] = *reinterpret_cast<const v4i*>(&sBh[bOff[i]]);
            bl[i] = *reinterpret_cast<const v4i*>(&sBl[bOff[i]]);
        }
        #pragma unroll
        for (int i = 0; i < 4; ++i)
            #pragma unroll
            for (int j = 0; j < 4; ++j) {
                MFMA_B16(acc[i][j], ah[i], bh[j]);
                MFMA_B16(acc[i][j], al[i], bh[j]);
                MFMA_B16(acc[i][j], ah[i], bl[j]);
            }
        __syncthreads();
    }

    asm volatile("s_nop 7\n\ts_nop 7\n\ts_nop 7" ::: "memory");  // MFMA->VALU hazard

    const int fq = lane >> 4;
    #pragma unroll
    for (int i = 0; i < 4; ++i) {
        const int row = m0 + wr * 64 + i * 16 + fq * 4;
        #pragma unroll
        for (int j = 0; j < 4; ++j) {
            const int col = n0 + wc * 64 + j * 16 + fr;
            #pragma unroll
            for (int r = 0; r < 4; ++r)
                C[(size_t)(row + r) * ldc + col] = acc[i][j][r];
        }
    }
}

// ===========================================================================
// Depthwise causal conv (width 4) + bias + SiLU. Input has leading dim xld.
// ===========================================================================
__global__ void conv_silu_kernel(const float* __restrict__ x_in, int xld,
                                 const float* __restrict__ w,
                                 const float* __restrict__ b,
                                 float* __restrict__ x_act) {
    const int idx = blockIdx.x * blockDim.x + threadIdx.x;
    const int ch = idx % D_INNER;
    const int m  = idx / D_INNER;
    const int t  = m % SEQ;

    float acc = b[ch];
    #pragma unroll
    for (int j = 0; j < D_CONV; ++j) {
        int tt = t - (D_CONV - 1) + j;
        if (tt >= 0)
            acc = fmaf(w[ch * D_CONV + j], x_in[(size_t)(m - (D_CONV - 1) + j) * xld + ch], acc);
    }
    x_act[idx] = acc / (1.f + __expf(-acc));
}

// ===========================================================================
// Chunked selective scan (3 kernels) — unchanged math from round 2.
// ===========================================================================
__global__ void scan_part1(const float* __restrict__ dt,
                           const float* __restrict__ x_act,
                           const float* __restrict__ dbc,
                           const float* __restrict__ A_log,
                           float* __restrict__ P, float* __restrict__ F) {
    __shared__ float Bsh[CLEN][D_STATE];
    const int tid = threadIdx.x;
    const int d = blockIdx.x * 256 + tid;
    const int c = blockIdx.y;
    const int b = blockIdx.z;
    const int mbase = b * SEQ + c * CLEN;

    {
        const int s = tid & 15, t0 = tid >> 4;
        #pragma unroll
        for (int q = 0; q < 4; ++q)
            Bsh[t0 + 16 * q][s] = dbc[(size_t)(mbase + t0 + 16 * q) * 96 + DT_RANK + s];
    }
    float A[16];
    #pragma unroll
    for (int q = 0; q < 4; ++q) {
        float4 v = *reinterpret_cast<const float4*>(&A_log[d * 16 + q * 4]);
        A[q*4+0] = -__expf(v.x); A[q*4+1] = -__expf(v.y);
        A[q*4+2] = -__expf(v.z); A[q*4+3] = -__expf(v.w);
    }
    __syncthreads();

    float h[16] = {};
    float Pp[16];
    #pragma unroll
    for (int s = 0; s < 16; ++s) Pp[s] = 1.f;

    for (int t = 0; t < CLEN; ++t) {
        const int m = mbase + t;
        const float dtv = dt[(size_t)m * D_INNER + d];
        const float u   = x_act[(size_t)m * D_INNER + d];
        const float du  = dtv * u;
        float Bv[16];
        #pragma unroll
        for (int q = 0; q < 4; ++q) {
            float4 v = *reinterpret_cast<const float4*>(&Bsh[t][q * 4]);
            Bv[q*4+0] = v.x; Bv[q*4+1] = v.y; Bv[q*4+2] = v.z; Bv[q*4+3] = v.w;
        }
        #pragma unroll
        for (int s = 0; s < 16; ++s) {
            const float dA = __expf(dtv * A[s]);
            Pp[s] *= dA;
            h[s] = fmaf(dA, h[s], du * Bv[s]);
        }
    }
    const size_t base = ((size_t)(b * NCHUNK + c) * 16) * D_INNER + d;
    #pragma unroll
    for (int s = 0; s < 16; ++s) {
        P[base + (size_t)s * D_INNER] = Pp[s];
        F[base + (size_t)s * D_INNER] = h[s];
    }
}

__global__ void scan_combine(const float* __restrict__ P, float* F) {
    const int idx = blockIdx.x * 256 + threadIdx.x;
    const int d  = idx % D_INNER;
    const int bs = idx / D_INNER;
    const int b  = bs >> 4, s = bs & 15;
    float G = 0.f;
    for (int c = 0; c < NCHUNK; ++c) {
        const size_t off = ((size_t)(b * NCHUNK + c) * 16 + s) * D_INNER + d;
        const float p = P[off], f = F[off];
        F[off] = G;
        G = fmaf(p, G, f);
    }
}

__global__ void scan_part2(const float* __restrict__ dt,
                           const float* __restrict__ x_act,
                           const float* __restrict__ dbc,
                           const float* __restrict__ A_log,
                           const float* __restrict__ Dp,
                           const float* __restrict__ Ginit,
                           const float* zp, int zld,   // may alias yf in fallback
                           float* yf) {
    __shared__ float BCs[CLEN][32];
    const int tid = threadIdx.x;
    const int d = blockIdx.x * 256 + tid;
    const int c = blockIdx.y;
    const int b = blockIdx.z;
    const int mbase = b * SEQ + c * CLEN;

    {
        const int t0 = tid >> 3;
        const int j  = (tid & 7) * 4;
        #pragma unroll
        for (int q = 0; q < 2; ++q) {
            float4 v = *reinterpret_cast<const float4*>(
                &dbc[(size_t)(mbase + t0 + 32 * q) * 96 + DT_RANK + j]);
            *reinterpret_cast<float4*>(&BCs[t0 + 32 * q][j]) = v;
        }
    }
    float A[16];
    #pragma unroll
    for (int q = 0; q < 4; ++q) {
        float4 v = *reinterpret_cast<const float4*>(&A_log[d * 16 + q * 4]);
        A[q*4+0] = -__expf(v.x); A[q*4+1] = -__expf(v.y);
        A[q*4+2] = -__expf(v.z); A[q*4+3] = -__expf(v.w);
    }
    float h[16];
    const size_t gbase = ((size_t)(b * NCHUNK + c) * 16) * D_INNER + d;
    #pragma unroll
    for (int s = 0; s < 16; ++s) h[s] = Ginit[gbase + (size_t)s * D_INNER];
    const float Dv = Dp[d];
    __syncthreads();

    for (int half = 0; half < 2; ++half) {
        const int tb = half * (CLEN / 2);
        float zreg[CLEN / 2];
        #pragma unroll
        for (int t = 0; t < CLEN / 2; ++t)
            zreg[t] = zp[(size_t)(mbase + tb + t) * zld + d];

        for (int t = 0; t < CLEN / 2; ++t) {
            const int m = mbase + tb + t;
            const float dtv = dt[(size_t)m * D_INNER + d];
            const float u   = x_act[(size_t)m * D_INNER + d];
            const float du  = dtv * u;
            float Bv[16], Cv[16];
            #pragma unroll
            for (int q = 0; q < 4; ++q) {
                float4 vb = *reinterpret_cast<const float4*>(&BCs[tb + t][q * 4]);
                float4 vc = *reinterpret_cast<const float4*>(&BCs[tb + t][16 + q * 4]);
                Bv[q*4+0] = vb.x; Bv[q*4+1] = vb.y; Bv[q*4+2] = vb.z; Bv[q*4+3] = vb.w;
                Cv[q*4+0] = vc.x; Cv[q*4+1] = vc.y; Cv[q*4+2] = vc.z; Cv[q*4+3] = vc.w;
            }
            float y0 = 0.f, y1 = 0.f;
            #pragma unroll
            for (int s = 0; s < 16; s += 2) {
                const float dA0 = __expf(dtv * A[s]);
                const float dA1 = __expf(dtv * A[s + 1]);
                h[s]     = fmaf(dA0, h[s],     du * Bv[s]);
                h[s + 1] = fmaf(dA1, h[s + 1], du * Bv[s + 1]);
                y0 = fmaf(h[s],     Cv[s],     y0);
                y1 = fmaf(h[s + 1], Cv[s + 1], y1);
            }
            float y = y0 + y1;
            y = fmaf(u, Dv, y);
            const float zv = zreg[t];
            const float g  = zv / (1.f + __expf(-zv));
            yf[(size_t)m * D_INNER + d] = y * g;
        }
    }
}

// ===========================================================================
extern "C" void kernel_launch(void* const* d_in, const int* in_sizes, int n_in,
                              void* d_out, int out_size, void* d_ws, size_t ws_size,
                              hipStream_t stream) {
    const float* x      = (const float*)d_in[0];
    const float* W_in   = (const float*)d_in[1];
    const float* conv_w = (const float*)d_in[2];
    const float* conv_b = (const float*)d_in[3];
    const float* W_x    = (const float*)d_in[4];
    const float* W_dt   = (const float*)d_in[5];
    const float* b_dt   = (const float*)d_in[6];
    const float* A_log  = (const float*)d_in[7];
    const float* Dp     = (const float*)d_in[8];
    const float* W_out  = (const float*)d_in[9];
    float* out = (float*)d_out;

    const size_t M1 = 1024u * 1024u;
    // fast-path sizes (floats / ushorts)
    const size_t fXZ = 8 * M1, fXACT = 4 * M1, fDBC = (size_t)BT * 96,
                 fDT = 4 * M1, fP = 1 * M1, fF = 1 * M1, fYF = 4 * M1;
    const size_t uX = 2 * M1, uW = 4 * M1;   // per hi/lo buffer
    const size_t need = (fXZ + fXACT + fDBC + fDT + fP + fF + fYF) * 4
                      + (2 * uX + 2 * uW) * 2;

    if (ws_size >= need) {
        // ------------------- fast path (split-bf16 MFMA projections) -------
        float* ws    = (float*)d_ws;
        float* xz    = ws;
        float* x_act = xz    + fXZ;
        float* dbc   = x_act + fXACT;
        float* dtbuf = dbc   + fDBC;
        float* Pbuf  = dtbuf + fDT;
        float* Fbuf  = Pbuf  + fP;
        float* yf    = Fbuf  + fF;
        u16* ub  = (u16*)(yf + fYF);
        u16* xhi = ub;            // 2M  (reused as W_out hi)
        u16* xlo = xhi + uX;      // 2M  (reused as W_out lo)
        u16* whi = xlo + uX;      // 4M  (reused as yf hi)
        u16* wlo = whi + uW;      // 4M  (reused as yf lo)

        // 1) split inputs of in_proj
        split_kernel<<<dim3((2 * M1) / 2048), 256, 0, stream>>>(x, xhi, xlo, 2 * M1);
        split_kernel<<<dim3((4 * M1) / 2048), 256, 0, stream>>>(W_in, whi, wlo, 4 * M1);

        // 2) in_proj: xz[2048][4096] = x @ W_in^T
        gemm_mfma3<<<dim3(4096 / 128, BT / 128), 256, 0, stream>>>(
            xhi, xlo, D_MODEL, whi, wlo, D_MODEL, xz, 4096, D_MODEL);

        // 3) conv + SiLU (x_in = xz[:, :2048])
        conv_silu_kernel<<<dim3((BT * D_INNER) / 256), 256, 0, stream>>>(
            xz, 4096, conv_w, conv_b, x_act);

        // 4) dbc = x_act @ W_x^T (fp32)
        gemm_nt<64,32,16,4,4,0><<<dim3(96 / 32, BT / 64), 128, 0, stream>>>(
            x_act, D_INNER, W_x, D_INNER, dbc, 96, D_INNER, nullptr);

        // 5) dt = softplus(dbc[:, :64] @ W_dt^T + b_dt) (fp32)
        gemm_nt<64,64,16,4,4,1><<<dim3(D_INNER / 64, BT / 64), 256, 0, stream>>>(
            dbc, 96, W_dt, DT_RANK, dtbuf, D_INNER, DT_RANK, b_dt);

        // 6) chunked scan + skip + gate (z = xz[:, 2048:])
        scan_part1<<<dim3(D_INNER / 256, NCHUNK, BATCH), 256, 0, stream>>>(
            dtbuf, x_act, dbc, A_log, Pbuf, Fbuf);
        scan_combine<<<dim3((BATCH * 16 * D_INNER) / 256), 256, 0, stream>>>(
            Pbuf, Fbuf);
        scan_part2<<<dim3(D_INNER / 256, NCHUNK, BATCH), 256, 0, stream>>>(
            dtbuf, x_act, dbc, A_log, Dp, Fbuf, xz + D_INNER, 4096, yf);

        // 7) split inputs of out_proj (reuse dead bf16 regions)
        split_kernel<<<dim3((4 * M1) / 2048), 256, 0, stream>>>(yf, whi, wlo, 4 * M1);
        split_kernel<<<dim3((2 * M1) / 2048), 256, 0, stream>>>(W_out, xhi, xlo, 2 * M1);

        // 8) out_proj: out = yf @ W_out^T
        gemm_mfma3<<<dim3(D_MODEL / 128, BT / 128), 256, 0, stream>>>(
            whi, wlo, D_INNER, xhi, xlo, D_INNER, out, D_MODEL, D_INNER);
    } else {
        // ------------------- fallback: all-fp32 path (round-2 version) ----
        float* ws    = (float*)d_ws;
        float* x_in  = ws;
        float* z     = x_in  + (size_t)BT * D_INNER;
        float* x_act = z     + (size_t)BT * D_INNER;
        float* dbc   = x_act + (size_t)BT * D_INNER;
        float* Pbuf  = dbc   + (size_t)BT * 96;
        float* Fbuf  = Pbuf  + (size_t)BATCH * NCHUNK * 16 * D_INNER;
        float* dtbuf = x_in;
        float* yf    = z;

        gemm_nt<64,64,16,4,4,0><<<dim3(D_INNER/64, BT/64), 256, 0, stream>>>(
            x, D_MODEL, W_in, D_MODEL, x_in, D_INNER, D_MODEL, nullptr);
        gemm_nt<64,64,16,4,4,0><<<dim3(D_INNER/64, BT/64), 256, 0, stream>>>(
            x, D_MODEL, W_in + (size_t)D_INNER * D_MODEL, D_MODEL, z, D_INNER, D_MODEL, nullptr);
        conv_silu_kernel<<<dim3((BT * D_INNER) / 256), 256, 0, stream>>>(
            x_in, D_INNER, conv_w, conv_b, x_act);
        gemm_nt<64,32,16,4,4,0><<<dim3(96/32, BT/64), 128, 0, stream>>>(
            x_act, D_INNER, W_x, D_INNER, dbc, 96, D_INNER, nullptr);
        gemm_nt<64,64,16,4,4,1><<<dim3(D_INNER/64, BT/64), 256, 0, stream>>>(
            dbc, 96, W_dt, DT_RANK, dtbuf, D_INNER, DT_RANK, b_dt);
        scan_part1<<<dim3(D_INNER/256, NCHUNK, BATCH), 256, 0, stream>>>(
            dtbuf, x_act, dbc, A_log, Pbuf, Fbuf);
        scan_combine<<<dim3((BATCH * 16 * D_INNER) / 256), 256, 0, stream>>>(
            Pbuf, Fbuf);
        scan_part2<<<dim3(D_INNER/256, NCHUNK, BATCH), 256, 0, stream>>>(
            dtbuf, x_act, dbc, A_log, Dp, Fbuf, z, D_INNER, yf);
        gemm_nt<64,64,16,4,4,0><<<dim3(D_MODEL/64, BT/64), 256, 0, stream>>>(
            yf, D_INNER, W_out, D_INNER, out, D_MODEL, D_INNER, nullptr);
    }
}

// Round 4
// 318.411 us; speedup vs baseline: 4.9180x; 1.5604x over previous
//
#include <hip/hip_runtime.h>
#include <math.h>

#define D_MODEL 1024
#define D_STATE 16
#define D_CONV  4
#define DT_RANK 64
#define D_INNER 2048
#define BATCH   2
#define SEQ     1024
#define BT      (BATCH*SEQ)   // 2048 rows
#define NCHUNK  16
#define CLEN    (SEQ/NCHUNK)  // 64
#define KSPLIT  16            // split-K factor for dbc GEMM

typedef int   v4i __attribute__((ext_vector_type(4)));
typedef float v4f __attribute__((ext_vector_type(4)));
typedef unsigned short u16;

// ===========================================================================
// fp32 GEMM (dt projection + fallback path)
// ===========================================================================
template<int BM, int BN, int BK, int TM, int TN, int EPI>
__launch_bounds__(256)
__global__ void gemm_nt(const float* __restrict__ A, int lda,
                        const float* __restrict__ B, int ldb,
                        float* __restrict__ C, int ldc,
                        int K, const float* __restrict__ bias) {
    constexpr int BX = BN / TN;
    constexpr int BY = BM / TM;
    constexpr int THREADS = BX * BY;

    __shared__ float As[BK][BM + 1];
    __shared__ float Bs[BK][BN + 1];

    const int tid = threadIdx.x;
    const int tx  = tid % BX;
    const int ty  = tid / BX;
    const int m0  = blockIdx.y * BM;
    const int n0  = blockIdx.x * BN;

    float acc[TM][TN] = {};

    for (int k0 = 0; k0 < K; k0 += BK) {
        #pragma unroll
        for (int l = 0; l < (BM * BK) / (THREADS * 4); ++l) {
            int idx = (tid + l * THREADS) * 4;
            int row = idx / BK, col = idx % BK;
            const float4 v = *reinterpret_cast<const float4*>(
                &A[(size_t)(m0 + row) * lda + k0 + col]);
            As[col + 0][row] = v.x; As[col + 1][row] = v.y;
            As[col + 2][row] = v.z; As[col + 3][row] = v.w;
        }
        #pragma unroll
        for (int l = 0; l < (BN * BK) / (THREADS * 4); ++l) {
            int idx = (tid + l * THREADS) * 4;
            int row = idx / BK, col = idx % BK;
            const float4 v = *reinterpret_cast<const float4*>(
                &B[(size_t)(n0 + row) * ldb + k0 + col]);
            Bs[col + 0][row] = v.x; Bs[col + 1][row] = v.y;
            Bs[col + 2][row] = v.z; Bs[col + 3][row] = v.w;
        }
        __syncthreads();

        #pragma unroll
        for (int kk = 0; kk < BK; ++kk) {
            float a[TM], b[TN];
            #pragma unroll
            for (int i = 0; i < TM; ++i) a[i] = As[kk][ty * TM + i];
            #pragma unroll
            for (int j = 0; j < TN; ++j) b[j] = Bs[kk][tx * TN + j];
            #pragma unroll
            for (int i = 0; i < TM; ++i)
                #pragma unroll
                for (int j = 0; j < TN; ++j)
                    acc[i][j] = fmaf(a[i], b[j], acc[i][j]);
        }
        __syncthreads();
    }

    #pragma unroll
    for (int i = 0; i < TM; ++i) {
        float* outp = &C[(size_t)(m0 + ty * TM + i) * ldc + n0 + tx * TN];
        float vals[4];
        #pragma unroll
        for (int j = 0; j < TN; ++j) {
            float val = acc[i][j];
            if (EPI == 1) {
                val += bias[n0 + tx * TN + j];
                val = (val > 20.f) ? val : log1pf(expf(val));
            }
            vals[j] = val;
        }
        float4 v;
        v.x = vals[0]; v.y = vals[1]; v.z = vals[2]; v.w = vals[3];
        *reinterpret_cast<float4*>(outp) = v;
    }
}

// ===========================================================================
// Split-K fp32 GEMM for the skinny dbc projection (N=96, K=2048).
// Grid (N/BN, M/BM, KSPLIT); each z computes a K-chunk into part[z][M][N].
// ===========================================================================
template<int BM, int BN, int BK, int TM, int TN>
__launch_bounds__(128)
__global__ void gemm_nt_splitk(const float* __restrict__ A, int lda,
                               const float* __restrict__ B, int ldb,
                               float* __restrict__ part, int N, int kchunk) {
    constexpr int BX = BN / TN;
    constexpr int BY = BM / TM;
    constexpr int THREADS = BX * BY;

    __shared__ float As[BK][BM + 1];
    __shared__ float Bs[BK][BN + 1];

    const int tid = threadIdx.x;
    const int tx  = tid % BX;
    const int ty  = tid / BX;
    const int m0  = blockIdx.y * BM;
    const int n0  = blockIdx.x * BN;
    const int kb  = blockIdx.z * kchunk;

    float acc[TM][TN] = {};

    for (int k0 = kb; k0 < kb + kchunk; k0 += BK) {
        #pragma unroll
        for (int l = 0; l < (BM * BK) / (THREADS * 4); ++l) {
            int idx = (tid + l * THREADS) * 4;
            int row = idx / BK, col = idx % BK;
            const float4 v = *reinterpret_cast<const float4*>(
                &A[(size_t)(m0 + row) * lda + k0 + col]);
            As[col + 0][row] = v.x; As[col + 1][row] = v.y;
            As[col + 2][row] = v.z; As[col + 3][row] = v.w;
        }
        #pragma unroll
        for (int l = 0; l < (BN * BK) / (THREADS * 4); ++l) {
            int idx = (tid + l * THREADS) * 4;
            int row = idx / BK, col = idx % BK;
            const float4 v = *reinterpret_cast<const float4*>(
                &B[(size_t)(n0 + row) * ldb + k0 + col]);
            Bs[col + 0][row] = v.x; Bs[col + 1][row] = v.y;
            Bs[col + 2][row] = v.z; Bs[col + 3][row] = v.w;
        }
        __syncthreads();

        #pragma unroll
        for (int kk = 0; kk < BK; ++kk) {
            float a[TM], b[TN];
            #pragma unroll
            for (int i = 0; i < TM; ++i) a[i] = As[kk][ty * TM + i];
            #pragma unroll
            for (int j = 0; j < TN; ++j) b[j] = Bs[kk][tx * TN + j];
            #pragma unroll
            for (int i = 0; i < TM; ++i)
                #pragma unroll
                for (int j = 0; j < TN; ++j)
                    acc[i][j] = fmaf(a[i], b[j], acc[i][j]);
        }
        __syncthreads();
    }

    float* base = part + (size_t)blockIdx.z * BT * N;
    #pragma unroll
    for (int i = 0; i < TM; ++i) {
        float* outp = &base[(size_t)(m0 + ty * TM + i) * N + n0 + tx * TN];
        float4 v;
        v.x = acc[i][0]; v.y = acc[i][1]; v.z = acc[i][2]; v.w = acc[i][3];
        *reinterpret_cast<float4*>(outp) = v;
    }
}

__global__ void reduce_splitk(const float* __restrict__ part,
                              float* __restrict__ outp, int n) {
    const int idx = blockIdx.x * 256 + threadIdx.x;
    if (idx >= n) return;
    float s = 0.f;
    #pragma unroll
    for (int kc = 0; kc < KSPLIT; ++kc)
        s += part[(size_t)kc * n + idx];
    outp[idx] = s;
}

// ===========================================================================
// fp32 -> (bf16 hi, bf16 lo) split, RNE. 8 elems/thread.
// ===========================================================================
__device__ __forceinline__ u16 rne_bf16(float x) {
    unsigned int u = __float_as_uint(x);
    unsigned int r = u + 0x7FFFu + ((u >> 16) & 1u);
    return (u16)(r >> 16);
}

__global__ void split_kernel(const float* __restrict__ in,
                             u16* __restrict__ hi, u16* __restrict__ lo, int n) {
    const int i = (blockIdx.x * 256 + threadIdx.x) * 8;
    if (i >= n) return;
    float4 a = *reinterpret_cast<const float4*>(&in[i]);
    float4 b = *reinterpret_cast<const float4*>(&in[i + 4]);
    float xs[8] = {a.x, a.y, a.z, a.w, b.x, b.y, b.z, b.w};
    unsigned int hw[4], lw[4];
    #pragma unroll
    for (int q = 0; q < 4; ++q) {
        u16 h0 = rne_bf16(xs[2*q]);
        u16 h1 = rne_bf16(xs[2*q+1]);
        float d0 = xs[2*q]   - __uint_as_float((unsigned int)h0 << 16);
        float d1 = xs[2*q+1] - __uint_as_float((unsigned int)h1 << 16);
        u16 l0 = rne_bf16(d0);
        u16 l1 = rne_bf16(d1);
        hw[q] = (unsigned int)h0 | ((unsigned int)h1 << 16);
        lw[q] = (unsigned int)l0 | ((unsigned int)l1 << 16);
    }
    *reinterpret_cast<v4i*>(&hi[i]) = *reinterpret_cast<v4i*>(hw);
    *reinterpret_cast<v4i*>(&lo[i]) = *reinterpret_cast<v4i*>(lw);
}

// ===========================================================================
// Split-bf16 MFMA GEMM: C = (Ahi+Alo) @ (Bhi+Blo)^T, fp32 accumulate.
// 128x128 tile, 4 waves, BK=32, LDS pitch 40 (conflict-free b128 ops).
// ===========================================================================
#define MFMA_B16(ACC, Af, Bf) \
    asm("v_mfma_f32_16x16x32_bf16 %0, %1, %2, %0" : "+v"(ACC) : "v"(Af), "v"(Bf))

__launch_bounds__(256)
__global__ void gemm_mfma3(const u16* __restrict__ Ahi, const u16* __restrict__ Alo, int lda,
                           const u16* __restrict__ Bhi, const u16* __restrict__ Blo, int ldb,
                           float* __restrict__ C, int ldc, int K) {
    __shared__ u16 smem[4 * 128 * 40];          // 40 KB
    u16* sAh = smem;
    u16* sAl = smem + 5120;
    u16* sBh = smem + 10240;
    u16* sBl = smem + 15360;

    const int tid  = threadIdx.x;
    const int lane = tid & 63;
    const int wave = tid >> 6;
    const int wr   = wave >> 1, wc = wave & 1;
    const int m0   = blockIdx.y * 128, n0 = blockIdx.x * 128;

    const int r0 = tid >> 2, s0 = tid & 3;
    const size_t aRow0 = (size_t)(m0 + r0) * lda + s0 * 8;
    const size_t aRow1 = aRow0 + (size_t)64 * lda;
    const size_t bRow0 = (size_t)(n0 + r0) * ldb + s0 * 8;
    const size_t bRow1 = bRow0 + (size_t)64 * ldb;
    const int w0 = r0 * 40 + s0 * 8;
    const int w1 = (r0 + 64) * 40 + s0 * 8;

    const int fr = lane & 15;
    const int fk = (lane >> 4) * 8;
    int aOff[4], bOff[4];
    #pragma unroll
    for (int i = 0; i < 4; ++i) {
        aOff[i] = (wr * 64 + i * 16 + fr) * 40 + fk;
        bOff[i] = (wc * 64 + i * 16 + fr) * 40 + fk;
    }

    v4f acc[4][4];
    #pragma unroll
    for (int i = 0; i < 4; ++i)
        #pragma unroll
        for (int j = 0; j < 4; ++j)
            acc[i][j] = (v4f)0.f;

    for (int k0 = 0; k0 < K; k0 += 32) {
        *reinterpret_cast<v4i*>(&sAh[w0]) = *reinterpret_cast<const v4i*>(&Ahi[aRow0 + k0]);
        *reinterpret_cast<v4i*>(&sAh[w1]) = *reinterpret_cast<const v4i*>(&Ahi[aRow1 + k0]);
        *reinterpret_cast<v4i*>(&sAl[w0]) = *reinterpret_cast<const v4i*>(&Alo[aRow0 + k0]);
        *reinterpret_cast<v4i*>(&sAl[w1]) = *reinterpret_cast<const v4i*>(&Alo[aRow1 + k0]);
        *reinterpret_cast<v4i*>(&sBh[w0]) = *reinterpret_cast<const v4i*>(&Bhi[bRow0 + k0]);
        *reinterpret_cast<v4i*>(&sBh[w1]) = *reinterpret_cast<const v4i*>(&Bhi[bRow1 + k0]);
        *reinterpret_cast<v4i*>(&sBl[w0]) = *reinterpret_cast<const v4i*>(&Blo[bRow0 + k0]);
        *reinterpret_cast<v4i*>(&sBl[w1]) = *reinterpret_cast<const v4i*>(&Blo[bRow1 + k0]);
        __syncthreads();

        v4i ah[4], al[4], bh[4], bl[4];
        #pragma unroll
        for (int i = 0; i < 4; ++i) {
            ah[i] = *reinterpret_cast<const v4i*>(&sAh[aOff[i]]);
            al[i] = *reinterpret_cast<const v4i*>(&sAl[aOff[i]]);
            bh[i] = *reinterpret_cast<const v4i*>(&sBh[bOff[i]]);
            bl[i] = *reinterpret_cast<const v4i*>(&sBl[bOff[i]]);
        }
        #pragma unroll
        for (int i = 0; i < 4; ++i)
            #pragma unroll
            for (int j = 0; j < 4; ++j) {
                MFMA_B16(acc[i][j], ah[i], bh[j]);
                MFMA_B16(acc[i][j], al[i], bh[j]);
                MFMA_B16(acc[i][j], ah[i], bl[j]);
            }
        __syncthreads();
    }

    asm volatile("s_nop 7\n\ts_nop 7\n\ts_nop 7" ::: "memory");

    const int fq = lane >> 4;
    #pragma unroll
    for (int i = 0; i < 4; ++i) {
        const int row = m0 + wr * 64 + i * 16 + fq * 4;
        #pragma unroll
        for (int j = 0; j < 4; ++j) {
            const int col = n0 + wc * 64 + j * 16 + fr;
            #pragma unroll
            for (int r = 0; r < 4; ++r)
                C[(size_t)(row + r) * ldc + col] = acc[i][j][r];
        }
    }
}

// ===========================================================================
// Depthwise causal conv (width 4) + bias + SiLU.
// ===========================================================================
__global__ void conv_silu_kernel(const float* __restrict__ x_in, int xld,
                                 const float* __restrict__ w,
                                 const float* __restrict__ b,
                                 float* __restrict__ x_act) {
    const int idx = blockIdx.x * blockDim.x + threadIdx.x;
    const int ch = idx % D_INNER;
    const int m  = idx / D_INNER;
    const int t  = m % SEQ;

    float acc = b[ch];
    #pragma unroll
    for (int j = 0; j < D_CONV; ++j) {
        int tt = t - (D_CONV - 1) + j;
        if (tt >= 0)
            acc = fmaf(w[ch * D_CONV + j], x_in[(size_t)(m - (D_CONV - 1) + j) * xld + ch], acc);
    }
    x_act[idx] = acc / (1.f + __expf(-acc));
}

// ===========================================================================
// Chunked selective scan (3 kernels).
// ===========================================================================
__global__ void scan_part1(const float* __restrict__ dt,
                           const float* __restrict__ x_act,
                           const float* __restrict__ dbc,
                           const float* __restrict__ A_log,
                           float* __restrict__ P, float* __restrict__ F) {
    __shared__ float Bsh[CLEN][D_STATE];
    const int tid = threadIdx.x;
    const int d = blockIdx.x * 256 + tid;
    const int c = blockIdx.y;
    const int b = blockIdx.z;
    const int mbase = b * SEQ + c * CLEN;

    {
        const int s = tid & 15, t0 = tid >> 4;
        #pragma unroll
        for (int q = 0; q < 4; ++q)
            Bsh[t0 + 16 * q][s] = dbc[(size_t)(mbase + t0 + 16 * q) * 96 + DT_RANK + s];
    }
    float A[16];
    #pragma unroll
    for (int q = 0; q < 4; ++q) {
        float4 v = *reinterpret_cast<const float4*>(&A_log[d * 16 + q * 4]);
        A[q*4+0] = -__expf(v.x); A[q*4+1] = -__expf(v.y);
        A[q*4+2] = -__expf(v.z); A[q*4+3] = -__expf(v.w);
    }
    __syncthreads();

    float h[16] = {};
    float Pp[16];
    #pragma unroll
    for (int s = 0; s < 16; ++s) Pp[s] = 1.f;

    for (int t = 0; t < CLEN; ++t) {
        const int m = mbase + t;
        const float dtv = dt[(size_t)m * D_INNER + d];
        const float u   = x_act[(size_t)m * D_INNER + d];
        const float du  = dtv * u;
        float Bv[16];
        #pragma unroll
        for (int q = 0; q < 4; ++q) {
            float4 v = *reinterpret_cast<const float4*>(&Bsh[t][q * 4]);
            Bv[q*4+0] = v.x; Bv[q*4+1] = v.y; Bv[q*4+2] = v.z; Bv[q*4+3] = v.w;
        }
        #pragma unroll
        for (int s = 0; s < 16; ++s) {
            const float dA = __expf(dtv * A[s]);
            Pp[s] *= dA;
            h[s] = fmaf(dA, h[s], du * Bv[s]);
        }
    }
    const size_t base = ((size_t)(b * NCHUNK + c) * 16) * D_INNER + d;
    #pragma unroll
    for (int s = 0; s < 16; ++s) {
        P[base + (size_t)s * D_INNER] = Pp[s];
        F[base + (size_t)s * D_INNER] = h[s];
    }
}

__global__ void scan_combine(const float* __restrict__ P, float* F) {
    const int idx = blockIdx.x * 256 + threadIdx.x;
    const int d  = idx % D_INNER;
    const int bs = idx / D_INNER;
    const int b  = bs >> 4, s = bs & 15;
    float G = 0.f;
    for (int c = 0; c < NCHUNK; ++c) {
        const size_t off = ((size_t)(b * NCHUNK + c) * 16 + s) * D_INNER + d;
        const float p = P[off], f = F[off];
        F[off] = G;
        G = fmaf(p, G, f);
    }
}

__global__ void scan_part2(const float* __restrict__ dt,
                           const float* __restrict__ x_act,
                           const float* __restrict__ dbc,
                           const float* __restrict__ A_log,
                           const float* __restrict__ Dp,
                           const float* __restrict__ Ginit,
                           const float* zp, int zld,
                           float* yf) {
    __shared__ float BCs[CLEN][32];
    const int tid = threadIdx.x;
    const int d = blockIdx.x * 256 + tid;
    const int c = blockIdx.y;
    const int b = blockIdx.z;
    const int mbase = b * SEQ + c * CLEN;

    {
        const int t0 = tid >> 3;
        const int j  = (tid & 7) * 4;
        #pragma unroll
        for (int q = 0; q < 2; ++q) {
            float4 v = *reinterpret_cast<const float4*>(
                &dbc[(size_t)(mbase + t0 + 32 * q) * 96 + DT_RANK + j]);
            *reinterpret_cast<float4*>(&BCs[t0 + 32 * q][j]) = v;
        }
    }
    float A[16];
    #pragma unroll
    for (int q = 0; q < 4; ++q) {
        float4 v = *reinterpret_cast<const float4*>(&A_log[d * 16 + q * 4]);
        A[q*4+0] = -__expf(v.x); A[q*4+1] = -__expf(v.y);
        A[q*4+2] = -__expf(v.z); A[q*4+3] = -__expf(v.w);
    }
    float h[16];
    const size_t gbase = ((size_t)(b * NCHUNK + c) * 16) * D_INNER + d;
    #pragma unroll
    for (int s = 0; s < 16; ++s) h[s] = Ginit[gbase + (size_t)s * D_INNER];
    const float Dv = Dp[d];
    __syncthreads();

    for (int half = 0; half < 2; ++half) {
        const int tb = half * (CLEN / 2);
        float zreg[CLEN / 2];
        #pragma unroll
        for (int t = 0; t < CLEN / 2; ++t)
            zreg[t] = zp[(size_t)(mbase + tb + t) * zld + d];

        for (int t = 0; t < CLEN / 2; ++t) {
            const int m = mbase + tb + t;
            const float dtv = dt[(size_t)m * D_INNER + d];
            const float u   = x_act[(size_t)m * D_INNER + d];
            const float du  = dtv * u;
            float Bv[16], Cv[16];
            #pragma unroll
            for (int q = 0; q < 4; ++q) {
                float4 vb = *reinterpret_cast<const float4*>(&BCs[tb + t][q * 4]);
                float4 vc = *reinterpret_cast<const float4*>(&BCs[tb + t][16 + q * 4]);
                Bv[q*4+0] = vb.x; Bv[q*4+1] = vb.y; Bv[q*4+2] = vb.z; Bv[q*4+3] = vb.w;
                Cv[q*4+0] = vc.x; Cv[q*4+1] = vc.y; Cv[q*4+2] = vc.z; Cv[q*4+3] = vc.w;
            }
            float y0 = 0.f, y1 = 0.f;
            #pragma unroll
            for (int s = 0; s < 16; s += 2) {
                const float dA0 = __expf(dtv * A[s]);
                const float dA1 = __expf(dtv * A[s + 1]);
                h[s]     = fmaf(dA0, h[s],     du * Bv[s]);
                h[s + 1] = fmaf(dA1, h[s + 1], du * Bv[s + 1]);
                y0 = fmaf(h[s],     Cv[s],     y0);
                y1 = fmaf(h[s + 1], Cv[s + 1], y1);
            }
            float y = y0 + y1;
            y = fmaf(u, Dv, y);
            const float zv = zreg[t];
            const float g  = zv / (1.f + __expf(-zv));
            yf[(size_t)m * D_INNER + d] = y * g;
        }
    }
}

// ===========================================================================
extern "C" void kernel_launch(void* const* d_in, const int* in_sizes, int n_in,
                              void* d_out, int out_size, void* d_ws, size_t ws_size,
                              hipStream_t stream) {
    const float* x      = (const float*)d_in[0];
    const float* W_in   = (const float*)d_in[1];
    const float* conv_w = (const float*)d_in[2];
    const float* conv_b = (const float*)d_in[3];
    const float* W_x    = (const float*)d_in[4];
    const float* W_dt   = (const float*)d_in[5];
    const float* b_dt   = (const float*)d_in[6];
    const float* A_log  = (const float*)d_in[7];
    const float* Dp     = (const float*)d_in[8];
    const float* W_out  = (const float*)d_in[9];
    float* out = (float*)d_out;

    const size_t M1 = 1024u * 1024u;
    const size_t fXZ = 8 * M1, fXACT = 4 * M1, fDBC = (size_t)BT * 96,
                 fDT = 4 * M1, fP = 1 * M1, fF = 1 * M1, fYF = 4 * M1;
    const size_t uX = 2 * M1, uW = 4 * M1;
    const size_t need = (fXZ + fXACT + fDBC + fDT + fP + fF + fYF) * 4
                      + (2 * uX + 2 * uW) * 2;

    if (ws_size >= need) {
        // ------------------- fast path -------------------------------------
        float* ws    = (float*)d_ws;
        float* xz    = ws;
        float* x_act = xz    + fXZ;
        float* dbc   = x_act + fXACT;
        float* dtbuf = dbc   + fDBC;
        float* Pbuf  = dtbuf + fDT;
        float* Fbuf  = Pbuf  + fP;
        float* yf    = Fbuf  + fF;
        u16* ub  = (u16*)(yf + fYF);
        u16* xhi = ub;
        u16* xlo = xhi + uX;
        u16* whi = xlo + uX;
        u16* wlo = whi + uW;
        // split-K partials for dbc (12.6 MB) alias the yf region (16 MB,
        // dead until scan_part2)
        float* dbc_part = yf;

        // 1) split inputs of in_proj
        split_kernel<<<dim3((2 * M1) / 2048), 256, 0, stream>>>(x, xhi, xlo, 2 * M1);
        split_kernel<<<dim3((4 * M1) / 2048), 256, 0, stream>>>(W_in, whi, wlo, 4 * M1);

        // 2) in_proj: xz[2048][4096] = x @ W_in^T
        gemm_mfma3<<<dim3(4096 / 128, BT / 128), 256, 0, stream>>>(
            xhi, xlo, D_MODEL, whi, wlo, D_MODEL, xz, 4096, D_MODEL);

        // 3) conv + SiLU (x_in = xz[:, :2048])
        conv_silu_kernel<<<dim3((BT * D_INNER) / 256), 256, 0, stream>>>(
            xz, 4096, conv_w, conv_b, x_act);

        // 4) dbc = x_act @ W_x^T (fp32, split-K for parallelism)
        gemm_nt_splitk<64,32,16,4,4><<<dim3(96 / 32, BT / 64, KSPLIT), 128, 0, stream>>>(
            x_act, D_INNER, W_x, D_INNER, dbc_part, 96, D_INNER / KSPLIT);
        reduce_splitk<<<dim3((BT * 96 + 255) / 256), 256, 0, stream>>>(
            dbc_part, dbc, BT * 96);

        // 5) dt = softplus(dbc[:, :64] @ W_dt^T + b_dt) (fp32)
        gemm_nt<64,64,16,4,4,1><<<dim3(D_INNER / 64, BT / 64), 256, 0, stream>>>(
            dbc, 96, W_dt, DT_RANK, dtbuf, D_INNER, DT_RANK, b_dt);

        // 6) chunked scan + skip + gate (z = xz[:, 2048:])
        scan_part1<<<dim3(D_INNER / 256, NCHUNK, BATCH), 256, 0, stream>>>(
            dtbuf, x_act, dbc, A_log, Pbuf, Fbuf);
        scan_combine<<<dim3((BATCH * 16 * D_INNER) / 256), 256, 0, stream>>>(
            Pbuf, Fbuf);
        scan_part2<<<dim3(D_INNER / 256, NCHUNK, BATCH), 256, 0, stream>>>(
            dtbuf, x_act, dbc, A_log, Dp, Fbuf, xz + D_INNER, 4096, yf);

        // 7) split inputs of out_proj (reuse dead bf16 regions)
        split_kernel<<<dim3((4 * M1) / 2048), 256, 0, stream>>>(yf, whi, wlo, 4 * M1);
        split_kernel<<<dim3((2 * M1) / 2048), 256, 0, stream>>>(W_out, xhi, xlo, 2 * M1);

        // 8) out_proj: out = yf @ W_out^T
        gemm_mfma3<<<dim3(D_MODEL / 128, BT / 128), 256, 0, stream>>>(
            whi, wlo, D_INNER, xhi, xlo, D_INNER, out, D_MODEL, D_INNER);
    } else {
        // ------------------- fallback: all-fp32 path -----------------------
        float* ws    = (float*)d_ws;
        float* x_in  = ws;
        float* z     = x_in  + (size_t)BT * D_INNER;
        float* x_act = z     + (size_t)BT * D_INNER;
        float* dbc   = x_act + (size_t)BT * D_INNER;
        float* Pbuf  = dbc   + (size_t)BT * 96;
        float* Fbuf  = Pbuf  + (size_t)BATCH * NCHUNK * 16 * D_INNER;
        float* dtbuf = x_in;
        float* yf    = z;

        gemm_nt<64,64,16,4,4,0><<<dim3(D_INNER/64, BT/64), 256, 0, stream>>>(
            x, D_MODEL, W_in, D_MODEL, x_in, D_INNER, D_MODEL, nullptr);
        gemm_nt<64,64,16,4,4,0><<<dim3(D_INNER/64, BT/64), 256, 0, stream>>>(
            x, D_MODEL, W_in + (size_t)D_INNER * D_MODEL, D_MODEL, z, D_INNER, D_MODEL, nullptr);
        conv_silu_kernel<<<dim3((BT * D_INNER) / 256), 256, 0, stream>>>(
            x_in, D_INNER, conv_w, conv_b, x_act);
        gemm_nt<64,32,16,4,4,0><<<dim3(96/32, BT/64), 128, 0, stream>>>(
            x_act, D_INNER, W_x, D_INNER, dbc, 96, D_INNER, nullptr);
        gemm_nt<64,64,16,4,4,1><<<dim3(D_INNER/64, BT/64), 256, 0, stream>>>(
            dbc, 96, W_dt, DT_RANK, dtbuf, D_INNER, DT_RANK, b_dt);
        scan_part1<<<dim3(D_INNER/256, NCHUNK, BATCH), 256, 0, stream>>>(
            dtbuf, x_act, dbc, A_log, Pbuf, Fbuf);
        scan_combine<<<dim3((BATCH * 16 * D_INNER) / 256), 256, 0, stream>>>(
            Pbuf, Fbuf);
        scan_part2<<<dim3(D_INNER/256, NCHUNK, BATCH), 256, 0, stream>>>(
            dtbuf, x_act, dbc, A_log, Dp, Fbuf, z, D_INNER, yf);
        gemm_nt<64,64,16,4,4,0><<<dim3(D_MODEL/64, BT/64), 256, 0, stream>>>(
            yf, D_INNER, W_out, D_INNER, out, D_MODEL, D_INNER, nullptr);
    }
}

// Round 5
// 253.160 us; speedup vs baseline: 6.1856x; 1.2577x over previous
//
#include <hip/hip_runtime.h>
#include <math.h>

#define D_MODEL 1024
#define D_STATE 16
#define D_CONV  4
#define DT_RANK 64
#define D_INNER 2048
#define BATCH   2
#define SEQ     1024
#define BT      (BATCH*SEQ)   // 2048 rows
#define NCHUNK  16
#define CLEN    (SEQ/NCHUNK)  // 64
#define KSPLIT  16            // split-K factor for dbc GEMM

typedef int   v4i __attribute__((ext_vector_type(4)));
typedef float v4f __attribute__((ext_vector_type(4)));
typedef unsigned short u16;

// ===========================================================================
// fp32 GEMM (dt projection + fallback path)
// ===========================================================================
template<int BM, int BN, int BK, int TM, int TN, int EPI>
__launch_bounds__(256)
__global__ void gemm_nt(const float* __restrict__ A, int lda,
                        const float* __restrict__ B, int ldb,
                        float* __restrict__ C, int ldc,
                        int K, const float* __restrict__ bias) {
    constexpr int BX = BN / TN;
    constexpr int BY = BM / TM;
    constexpr int THREADS = BX * BY;

    __shared__ float As[BK][BM + 1];
    __shared__ float Bs[BK][BN + 1];

    const int tid = threadIdx.x;
    const int tx  = tid % BX;
    const int ty  = tid / BX;
    const int m0  = blockIdx.y * BM;
    const int n0  = blockIdx.x * BN;

    float acc[TM][TN] = {};

    for (int k0 = 0; k0 < K; k0 += BK) {
        #pragma unroll
        for (int l = 0; l < (BM * BK) / (THREADS * 4); ++l) {
            int idx = (tid + l * THREADS) * 4;
            int row = idx / BK, col = idx % BK;
            const float4 v = *reinterpret_cast<const float4*>(
                &A[(size_t)(m0 + row) * lda + k0 + col]);
            As[col + 0][row] = v.x; As[col + 1][row] = v.y;
            As[col + 2][row] = v.z; As[col + 3][row] = v.w;
        }
        #pragma unroll
        for (int l = 0; l < (BN * BK) / (THREADS * 4); ++l) {
            int idx = (tid + l * THREADS) * 4;
            int row = idx / BK, col = idx % BK;
            const float4 v = *reinterpret_cast<const float4*>(
                &B[(size_t)(n0 + row) * ldb + k0 + col]);
            Bs[col + 0][row] = v.x; Bs[col + 1][row] = v.y;
            Bs[col + 2][row] = v.z; Bs[col + 3][row] = v.w;
        }
        __syncthreads();

        #pragma unroll
        for (int kk = 0; kk < BK; ++kk) {
            float a[TM], b[TN];
            #pragma unroll
            for (int i = 0; i < TM; ++i) a[i] = As[kk][ty * TM + i];
            #pragma unroll
            for (int j = 0; j < TN; ++j) b[j] = Bs[kk][tx * TN + j];
            #pragma unroll
            for (int i = 0; i < TM; ++i)
                #pragma unroll
                for (int j = 0; j < TN; ++j)
                    acc[i][j] = fmaf(a[i], b[j], acc[i][j]);
        }
        __syncthreads();
    }

    #pragma unroll
    for (int i = 0; i < TM; ++i) {
        float* outp = &C[(size_t)(m0 + ty * TM + i) * ldc + n0 + tx * TN];
        float vals[4];
        #pragma unroll
        for (int j = 0; j < TN; ++j) {
            float val = acc[i][j];
            if (EPI == 1) {
                val += bias[n0 + tx * TN + j];
                val = (val > 20.f) ? val : log1pf(expf(val));
            }
            vals[j] = val;
        }
        float4 v;
        v.x = vals[0]; v.y = vals[1]; v.z = vals[2]; v.w = vals[3];
        *reinterpret_cast<float4*>(outp) = v;
    }
}

// ===========================================================================
// Split-K fp32 GEMM for the skinny dbc projection (N=96, K=2048).
// ===========================================================================
template<int BM, int BN, int BK, int TM, int TN>
__launch_bounds__(128)
__global__ void gemm_nt_splitk(const float* __restrict__ A, int lda,
                               const float* __restrict__ B, int ldb,
                               float* __restrict__ part, int N, int kchunk) {
    constexpr int BX = BN / TN;
    constexpr int BY = BM / TM;
    constexpr int THREADS = BX * BY;

    __shared__ float As[BK][BM + 1];
    __shared__ float Bs[BK][BN + 1];

    const int tid = threadIdx.x;
    const int tx  = tid % BX;
    const int ty  = tid / BX;
    const int m0  = blockIdx.y * BM;
    const int n0  = blockIdx.x * BN;
    const int kb  = blockIdx.z * kchunk;

    float acc[TM][TN] = {};

    for (int k0 = kb; k0 < kb + kchunk; k0 += BK) {
        #pragma unroll
        for (int l = 0; l < (BM * BK) / (THREADS * 4); ++l) {
            int idx = (tid + l * THREADS) * 4;
            int row = idx / BK, col = idx % BK;
            const float4 v = *reinterpret_cast<const float4*>(
                &A[(size_t)(m0 + row) * lda + k0 + col]);
            As[col + 0][row] = v.x; As[col + 1][row] = v.y;
            As[col + 2][row] = v.z; As[col + 3][row] = v.w;
        }
        #pragma unroll
        for (int l = 0; l < (BN * BK) / (THREADS * 4); ++l) {
            int idx = (tid + l * THREADS) * 4;
            int row = idx / BK, col = idx % BK;
            const float4 v = *reinterpret_cast<const float4*>(
                &B[(size_t)(n0 + row) * ldb + k0 + col]);
            Bs[col + 0][row] = v.x; Bs[col + 1][row] = v.y;
            Bs[col + 2][row] = v.z; Bs[col + 3][row] = v.w;
        }
        __syncthreads();

        #pragma unroll
        for (int kk = 0; kk < BK; ++kk) {
            float a[TM], b[TN];
            #pragma unroll
            for (int i = 0; i < TM; ++i) a[i] = As[kk][ty * TM + i];
            #pragma unroll
            for (int j = 0; j < TN; ++j) b[j] = Bs[kk][tx * TN + j];
            #pragma unroll
            for (int i = 0; i < TM; ++i)
                #pragma unroll
                for (int j = 0; j < TN; ++j)
                    acc[i][j] = fmaf(a[i], b[j], acc[i][j]);
        }
        __syncthreads();
    }

    float* base = part + (size_t)blockIdx.z * BT * N;
    #pragma unroll
    for (int i = 0; i < TM; ++i) {
        float* outp = &base[(size_t)(m0 + ty * TM + i) * N + n0 + tx * TN];
        float4 v;
        v.x = acc[i][0]; v.y = acc[i][1]; v.z = acc[i][2]; v.w = acc[i][3];
        *reinterpret_cast<float4*>(outp) = v;
    }
}

__global__ void reduce_splitk(const float* __restrict__ part,
                              float* __restrict__ outp, int n) {
    const int idx = blockIdx.x * 256 + threadIdx.x;
    if (idx >= n) return;
    float s = 0.f;
    #pragma unroll
    for (int kc = 0; kc < KSPLIT; ++kc)
        s += part[(size_t)kc * n + idx];
    outp[idx] = s;
}

// ===========================================================================
// bf16 helpers
// ===========================================================================
__device__ __forceinline__ u16 rne_bf16(float x) {
    unsigned int u = __float_as_uint(x);
    unsigned int r = u + 0x7FFFu + ((u >> 16) & 1u);
    return (u16)(r >> 16);
}

// One pass converting: x -> (hi,lo); W_in -> hi; W_out -> hi.
// Segments (elements): [0,2M) x | [2M,6M) W_in | [6M,8M) W_out
__global__ void prep_kernel(const float* __restrict__ x,
                            const float* __restrict__ Win,
                            const float* __restrict__ Wout,
                            u16* __restrict__ xhi, u16* __restrict__ xlo,
                            u16* __restrict__ winh, u16* __restrict__ wouth) {
    const size_t M2 = 2u * 1024u * 1024u;
    size_t i = ((size_t)blockIdx.x * 256 + threadIdx.x) * 8;
    if (i < M2) {
        // x: hi + lo
        float4 a = *reinterpret_cast<const float4*>(&x[i]);
        float4 b = *reinterpret_cast<const float4*>(&x[i + 4]);
        float xs[8] = {a.x, a.y, a.z, a.w, b.x, b.y, b.z, b.w};
        unsigned int hw[4], lw[4];
        #pragma unroll
        for (int q = 0; q < 4; ++q) {
            u16 h0 = rne_bf16(xs[2*q]);
            u16 h1 = rne_bf16(xs[2*q+1]);
            float d0 = xs[2*q]   - __uint_as_float((unsigned int)h0 << 16);
            float d1 = xs[2*q+1] - __uint_as_float((unsigned int)h1 << 16);
            hw[q] = (unsigned int)h0 | ((unsigned int)rne_bf16(0.f + 0.f + h1) << 16);
            // NOTE: keep simple & correct:
            hw[q] = (unsigned int)h0 | ((unsigned int)h1 << 16);
            lw[q] = (unsigned int)rne_bf16(d0) | ((unsigned int)rne_bf16(d1) << 16);
        }
        *reinterpret_cast<v4i*>(&xhi[i]) = *reinterpret_cast<v4i*>(hw);
        *reinterpret_cast<v4i*>(&xlo[i]) = *reinterpret_cast<v4i*>(lw);
    } else if (i < 3 * M2) {
        size_t j = i - M2;
        float4 a = *reinterpret_cast<const float4*>(&Win[j]);
        float4 b = *reinterpret_cast<const float4*>(&Win[j + 4]);
        float xs[8] = {a.x, a.y, a.z, a.w, b.x, b.y, b.z, b.w};
        unsigned int hw[4];
        #pragma unroll
        for (int q = 0; q < 4; ++q)
            hw[q] = (unsigned int)rne_bf16(xs[2*q]) | ((unsigned int)rne_bf16(xs[2*q+1]) << 16);
        *reinterpret_cast<v4i*>(&winh[j]) = *reinterpret_cast<v4i*>(hw);
    } else {
        size_t j = i - 3 * M2;
        float4 a = *reinterpret_cast<const float4*>(&Wout[j]);
        float4 b = *reinterpret_cast<const float4*>(&Wout[j + 4]);
        float xs[8] = {a.x, a.y, a.z, a.w, b.x, b.y, b.z, b.w};
        unsigned int hw[4];
        #pragma unroll
        for (int q = 0; q < 4; ++q)
            hw[q] = (unsigned int)rne_bf16(xs[2*q]) | ((unsigned int)rne_bf16(xs[2*q+1]) << 16);
        *reinterpret_cast<v4i*>(&wouth[j]) = *reinterpret_cast<v4i*>(hw);
    }
}

// ===========================================================================
// 2-term split-bf16 MFMA GEMM: C = (Ahi+Alo) @ Bhi^T, fp32 accumulate.
// 4 waves in (BM/WM)x(BN/WN)=2x2; LDS double-buffered, one barrier/iter;
// global loads for k+1 issued before the MFMA block of k (latency hiding).
// LDS row pitch 40 shorts (80 B) - conflict-light b128 ops.
// ===========================================================================
#define MFMA_B16(ACC, Af, Bf) \
    asm("v_mfma_f32_16x16x32_bf16 %0, %1, %2, %0" : "+v"(ACC) : "v"(Af), "v"(Bf))

template<int BM, int BN, int WM, int WN>
__launch_bounds__(256)
__global__ void gemm_mfma2(const u16* __restrict__ Ahi, const u16* __restrict__ Alo, int lda,
                           const u16* __restrict__ Bhi, int ldb,
                           float* __restrict__ C, int ldc, int K) {
    constexpr int ACH = BM / 64;          // 16B chunks per thread per A-buf
    constexpr int BCH = BN / 64;
    constexpr int WMF = WM / 16;
    constexpr int WNF = WN / 16;
    constexpr int SA  = BM * 40;          // shorts per A component
    constexpr int SB  = BN * 40;
    constexpr int BUFSZ = 2 * SA + SB;
    constexpr int WCOLS = BN / WN;

    __shared__ u16 smem[2 * BUFSZ];

    const int tid  = threadIdx.x;
    const int lane = tid & 63;
    const int wave = tid >> 6;
    const int wr   = wave / WCOLS, wc = wave % WCOLS;
    const int m0   = blockIdx.y * BM, n0 = blockIdx.x * BN;

    size_t aBase[ACH]; int aW[ACH];
    #pragma unroll
    for (int q = 0; q < ACH; ++q) {
        int c = tid + q * 256, row = c >> 2, slot = c & 3;
        aBase[q] = (size_t)(m0 + row) * lda + slot * 8;
        aW[q] = row * 40 + slot * 8;
    }
    size_t bBase[BCH]; int bW[BCH];
    #pragma unroll
    for (int q = 0; q < BCH; ++q) {
        int c = tid + q * 256, row = c >> 2, slot = c & 3;
        bBase[q] = (size_t)(n0 + row) * ldb + slot * 8;
        bW[q] = row * 40 + slot * 8;
    }

    const int fr = lane & 15;
    const int fk = (lane >> 4) * 8;
    const int fq = lane >> 4;
    int aOff[WMF], bOff[WNF];
    #pragma unroll
    for (int i = 0; i < WMF; ++i) aOff[i] = (wr * WM + i * 16 + fr) * 40 + fk;
    #pragma unroll
    for (int j = 0; j < WNF; ++j) bOff[j] = (wc * WN + j * 16 + fr) * 40 + fk;

    v4f acc[WMF][WNF];
    #pragma unroll
    for (int i = 0; i < WMF; ++i)
        #pragma unroll
        for (int j = 0; j < WNF; ++j)
            acc[i][j] = (v4f)0.f;

    v4i rAh[ACH], rAl[ACH], rBh[BCH];
    // prolog: stage k=0 into buf0
    #pragma unroll
    for (int q = 0; q < ACH; ++q) {
        rAh[q] = *reinterpret_cast<const v4i*>(Ahi + aBase[q]);
        rAl[q] = *reinterpret_cast<const v4i*>(Alo + aBase[q]);
    }
    #pragma unroll
    for (int q = 0; q < BCH; ++q)
        rBh[q] = *reinterpret_cast<const v4i*>(Bhi + bBase[q]);
    #pragma unroll
    for (int q = 0; q < ACH; ++q) {
        *reinterpret_cast<v4i*>(&smem[aW[q]]) = rAh[q];
        *reinterpret_cast<v4i*>(&smem[SA + aW[q]]) = rAl[q];
    }
    #pragma unroll
    for (int q = 0; q < BCH; ++q)
        *reinterpret_cast<v4i*>(&smem[2 * SA + bW[q]]) = rBh[q];
    __syncthreads();

    const int NK = K / 32;
    for (int k = 0; k < NK; ++k) {
        u16* sc = smem + (k & 1) * BUFSZ;
        if (k + 1 < NK) {   // issue next-tile global loads early
            const int k0 = (k + 1) * 32;
            #pragma unroll
            for (int q = 0; q < ACH; ++q) {
                rAh[q] = *reinterpret_cast<const v4i*>(Ahi + aBase[q] + k0);
                rAl[q] = *reinterpret_cast<const v4i*>(Alo + aBase[q] + k0);
            }
            #pragma unroll
            for (int q = 0; q < BCH; ++q)
                rBh[q] = *reinterpret_cast<const v4i*>(Bhi + bBase[q] + k0);
        }

        v4i ah[WMF], al[WMF];
        #pragma unroll
        for (int i = 0; i < WMF; ++i) {
            ah[i] = *reinterpret_cast<const v4i*>(&sc[aOff[i]]);
            al[i] = *reinterpret_cast<const v4i*>(&sc[SA + aOff[i]]);
        }
        #pragma unroll
        for (int j = 0; j < WNF; ++j) {
            v4i bh = *reinterpret_cast<const v4i*>(&sc[2 * SA + bOff[j]]);
            #pragma unroll
            for (int i = 0; i < WMF; ++i) {
                MFMA_B16(acc[i][j], ah[i], bh);
                MFMA_B16(acc[i][j], al[i], bh);
            }
        }

        if (k + 1 < NK) {
            u16* sn = smem + ((k + 1) & 1) * BUFSZ;
            #pragma unroll
            for (int q = 0; q < ACH; ++q) {
                *reinterpret_cast<v4i*>(&sn[aW[q]]) = rAh[q];
                *reinterpret_cast<v4i*>(&sn[SA + aW[q]]) = rAl[q];
            }
            #pragma unroll
            for (int q = 0; q < BCH; ++q)
                *reinterpret_cast<v4i*>(&sn[2 * SA + bW[q]]) = rBh[q];
            __syncthreads();
        }
    }

    asm volatile("s_nop 7\n\ts_nop 7\n\ts_nop 7" ::: "memory");  // MFMA->VALU hazard

    #pragma unroll
    for (int i = 0; i < WMF; ++i) {
        const int row = m0 + wr * WM + i * 16 + fq * 4;
        #pragma unroll
        for (int j = 0; j < WNF; ++j) {
            const int col = n0 + wc * WN + j * 16 + fr;
            #pragma unroll
            for (int r = 0; r < 4; ++r)
                C[(size_t)(row + r) * ldc + col] = acc[i][j][r];
        }
    }
}

// ===========================================================================
// Depthwise causal conv (width 4) + bias + SiLU.
// ===========================================================================
__global__ void conv_silu_kernel(const float* __restrict__ x_in, int xld,
                                 const float* __restrict__ w,
                                 const float* __restrict__ b,
                                 float* __restrict__ x_act) {
    const int idx = blockIdx.x * blockDim.x + threadIdx.x;
    const int ch = idx % D_INNER;
    const int m  = idx / D_INNER;
    const int t  = m % SEQ;

    float acc = b[ch];
    #pragma unroll
    for (int j = 0; j < D_CONV; ++j) {
        int tt = t - (D_CONV - 1) + j;
        if (tt >= 0)
            acc = fmaf(w[ch * D_CONV + j], x_in[(size_t)(m - (D_CONV - 1) + j) * xld + ch], acc);
    }
    x_act[idx] = acc / (1.f + __expf(-acc));
}

// ===========================================================================
// Chunked selective scan (3 kernels).
// ===========================================================================
__global__ void scan_part1(const float* __restrict__ dt,
                           const float* __restrict__ x_act,
                           const float* __restrict__ dbc,
                           const float* __restrict__ A_log,
                           float* __restrict__ P, float* __restrict__ F) {
    __shared__ float Bsh[CLEN][D_STATE];
    const int tid = threadIdx.x;
    const int d = blockIdx.x * 256 + tid;
    const int c = blockIdx.y;
    const int b = blockIdx.z;
    const int mbase = b * SEQ + c * CLEN;

    {
        const int s = tid & 15, t0 = tid >> 4;
        #pragma unroll
        for (int q = 0; q < 4; ++q)
            Bsh[t0 + 16 * q][s] = dbc[(size_t)(mbase + t0 + 16 * q) * 96 + DT_RANK + s];
    }
    float A[16];
    #pragma unroll
    for (int q = 0; q < 4; ++q) {
        float4 v = *reinterpret_cast<const float4*>(&A_log[d * 16 + q * 4]);
        A[q*4+0] = -__expf(v.x); A[q*4+1] = -__expf(v.y);
        A[q*4+2] = -__expf(v.z); A[q*4+3] = -__expf(v.w);
    }
    __syncthreads();

    float h[16] = {};
    float Pp[16];
    #pragma unroll
    for (int s = 0; s < 16; ++s) Pp[s] = 1.f;

    for (int t = 0; t < CLEN; ++t) {
        const int m = mbase + t;
        const float dtv = dt[(size_t)m * D_INNER + d];
        const float u   = x_act[(size_t)m * D_INNER + d];
        const float du  = dtv * u;
        float Bv[16];
        #pragma unroll
        for (int q = 0; q < 4; ++q) {
            float4 v = *reinterpret_cast<const float4*>(&Bsh[t][q * 4]);
            Bv[q*4+0] = v.x; Bv[q*4+1] = v.y; Bv[q*4+2] = v.z; Bv[q*4+3] = v.w;
        }
        #pragma unroll
        for (int s = 0; s < 16; ++s) {
            const float dA = __expf(dtv * A[s]);
            Pp[s] *= dA;
            h[s] = fmaf(dA, h[s], du * Bv[s]);
        }
    }
    const size_t base = ((size_t)(b * NCHUNK + c) * 16) * D_INNER + d;
    #pragma unroll
    for (int s = 0; s < 16; ++s) {
        P[base + (size_t)s * D_INNER] = Pp[s];
        F[base + (size_t)s * D_INNER] = h[s];
    }
}

__global__ void scan_combine(const float* __restrict__ P, float* F) {
    const int idx = blockIdx.x * 256 + threadIdx.x;
    const int d  = idx % D_INNER;
    const int bs = idx / D_INNER;
    const int b  = bs >> 4, s = bs & 15;
    float G = 0.f;
    for (int c = 0; c < NCHUNK; ++c) {
        const size_t off = ((size_t)(b * NCHUNK + c) * 16 + s) * D_INNER + d;
        const float p = P[off], f = F[off];
        F[off] = G;
        G = fmaf(p, G, f);
    }
}

// BF16OUT=1: write yf as bf16 (hi,lo) pair for the MFMA out_proj.
// BF16OUT=0: write fp32 yf (fallback path; zp may alias yf -> z preloaded).
template<int BF16OUT>
__global__ void scan_part2(const float* __restrict__ dt,
                           const float* __restrict__ x_act,
                           const float* __restrict__ dbc,
                           const float* __restrict__ A_log,
                           const float* __restrict__ Dp,
                           const float* __restrict__ Ginit,
                           const float* zp, int zld,
                           float* yf, u16* yh, u16* yl) {
    __shared__ float BCs[CLEN][32];
    const int tid = threadIdx.x;
    const int d = blockIdx.x * 256 + tid;
    const int c = blockIdx.y;
    const int b = blockIdx.z;
    const int mbase = b * SEQ + c * CLEN;

    {
        const int t0 = tid >> 3;
        const int j  = (tid & 7) * 4;
        #pragma unroll
        for (int q = 0; q < 2; ++q) {
            float4 v = *reinterpret_cast<const float4*>(
                &dbc[(size_t)(mbase + t0 + 32 * q) * 96 + DT_RANK + j]);
            *reinterpret_cast<float4*>(&BCs[t0 + 32 * q][j]) = v;
        }
    }
    float A[16];
    #pragma unroll
    for (int q = 0; q < 4; ++q) {
        float4 v = *reinterpret_cast<const float4*>(&A_log[d * 16 + q * 4]);
        A[q*4+0] = -__expf(v.x); A[q*4+1] = -__expf(v.y);
        A[q*4+2] = -__expf(v.z); A[q*4+3] = -__expf(v.w);
    }
    float h[16];
    const size_t gbase = ((size_t)(b * NCHUNK + c) * 16) * D_INNER + d;
    #pragma unroll
    for (int s = 0; s < 16; ++s) h[s] = Ginit[gbase + (size_t)s * D_INNER];
    const float Dv = Dp[d];
    __syncthreads();

    for (int half = 0; half < 2; ++half) {
        const int tb = half * (CLEN / 2);
        float zreg[CLEN / 2];
        #pragma unroll
        for (int t = 0; t < CLEN / 2; ++t)
            zreg[t] = zp[(size_t)(mbase + tb + t) * zld + d];

        for (int t = 0; t < CLEN / 2; ++t) {
            const int m = mbase + tb + t;
            const float dtv = dt[(size_t)m * D_INNER + d];
            const float u   = x_act[(size_t)m * D_INNER + d];
            const float du  = dtv * u;
            float Bv[16], Cv[16];
            #pragma unroll
            for (int q = 0; q < 4; ++q) {
                float4 vb = *reinterpret_cast<const float4*>(&BCs[tb + t][q * 4]);
                float4 vc = *reinterpret_cast<const float4*>(&BCs[tb + t][16 + q * 4]);
                Bv[q*4+0] = vb.x; Bv[q*4+1] = vb.y; Bv[q*4+2] = vb.z; Bv[q*4+3] = vb.w;
                Cv[q*4+0] = vc.x; Cv[q*4+1] = vc.y; Cv[q*4+2] = vc.z; Cv[q*4+3] = vc.w;
            }
            float y0 = 0.f, y1 = 0.f;
            #pragma unroll
            for (int s = 0; s < 16; s += 2) {
                const float dA0 = __expf(dtv * A[s]);
                const float dA1 = __expf(dtv * A[s + 1]);
                h[s]     = fmaf(dA0, h[s],     du * Bv[s]);
                h[s + 1] = fmaf(dA1, h[s + 1], du * Bv[s + 1]);
                y0 = fmaf(h[s],     Cv[s],     y0);
                y1 = fmaf(h[s + 1], Cv[s + 1], y1);
            }
            float y = y0 + y1;
            y = fmaf(u, Dv, y);
            const float zv = zreg[t];
            const float g  = zv / (1.f + __expf(-zv));
            const float val = y * g;
            if (BF16OUT) {
                const u16 hh = rne_bf16(val);
                yh[(size_t)m * D_INNER + d] = hh;
                yl[(size_t)m * D_INNER + d] =
                    rne_bf16(val - __uint_as_float((unsigned int)hh << 16));
            } else {
                yf[(size_t)m * D_INNER + d] = val;
            }
        }
    }
}

// ===========================================================================
extern "C" void kernel_launch(void* const* d_in, const int* in_sizes, int n_in,
                              void* d_out, int out_size, void* d_ws, size_t ws_size,
                              hipStream_t stream) {
    const float* x      = (const float*)d_in[0];
    const float* W_in   = (const float*)d_in[1];
    const float* conv_w = (const float*)d_in[2];
    const float* conv_b = (const float*)d_in[3];
    const float* W_x    = (const float*)d_in[4];
    const float* W_dt   = (const float*)d_in[5];
    const float* b_dt   = (const float*)d_in[6];
    const float* A_log  = (const float*)d_in[7];
    const float* Dp     = (const float*)d_in[8];
    const float* W_out  = (const float*)d_in[9];
    float* out = (float*)d_out;

    const size_t M1 = 1024u * 1024u;
    // floats: xz 8M | x_act 4M | dbc .1875M | dt 4M | P 1M | F 1M
    // shorts: xhi 2M | xlo 2M | winh 4M | wouth 2M | yh 4M | yl 4M
    const size_t fXZ = 8 * M1, fXACT = 4 * M1, fDBC = (size_t)BT * 96,
                 fDT = 4 * M1, fP = 1 * M1, fF = 1 * M1;
    const size_t need = (fXZ + fXACT + fDBC + fDT + fP + fF) * 4 + 18 * M1 * 2;

    if (ws_size >= need) {
        float* ws    = (float*)d_ws;
        float* xz    = ws;
        float* x_act = xz    + fXZ;
        float* dbc   = x_act + fXACT;
        float* dtbuf = dbc   + fDBC;
        float* Pbuf  = dtbuf + fDT;
        float* Fbuf  = Pbuf  + fP;
        u16* xhi   = (u16*)(Fbuf + fF);
        u16* xlo   = xhi   + 2 * M1;
        u16* winh  = xlo   + 2 * M1;
        u16* wouth = winh  + 4 * M1;
        u16* yh    = wouth + 2 * M1;   // 4M shorts
        u16* yl    = yh    + 4 * M1;   // 4M shorts
        // dbc split-K partials (12.6 MB) alias yh/yl (16 MB, dead until scan_part2)
        float* dbc_part = (float*)yh;

        // 1) convert: x -> hi/lo, W_in -> hi, W_out -> hi (one pass)
        prep_kernel<<<dim3((8 * M1) / 2048), 256, 0, stream>>>(
            x, W_in, W_out, xhi, xlo, winh, wouth);

        // 2) in_proj: xz[2048][4096] = x @ W_in^T   (128x256 tile, 2-term)
        gemm_mfma2<128, 256, 64, 128><<<dim3(4096 / 256, BT / 128), 256, 0, stream>>>(
            xhi, xlo, D_MODEL, winh, D_MODEL, xz, 4096, D_MODEL);

        // 3) conv + SiLU (x_in = xz[:, :2048])
        conv_silu_kernel<<<dim3((BT * D_INNER) / 256), 256, 0, stream>>>(
            xz, 4096, conv_w, conv_b, x_act);

        // 4) dbc = x_act @ W_x^T (fp32 split-K)
        gemm_nt_splitk<64,32,16,4,4><<<dim3(96 / 32, BT / 64, KSPLIT), 128, 0, stream>>>(
            x_act, D_INNER, W_x, D_INNER, dbc_part, 96, D_INNER / KSPLIT);
        reduce_splitk<<<dim3((BT * 96 + 255) / 256), 256, 0, stream>>>(
            dbc_part, dbc, BT * 96);

        // 5) dt = softplus(dbc[:, :64] @ W_dt^T + b_dt) (fp32)
        gemm_nt<64,64,16,4,4,1><<<dim3(D_INNER / 64, BT / 64), 256, 0, stream>>>(
            dbc, 96, W_dt, DT_RANK, dtbuf, D_INNER, DT_RANK, b_dt);

        // 6) chunked scan + skip + gate; emit yf as bf16 hi/lo
        scan_part1<<<dim3(D_INNER / 256, NCHUNK, BATCH), 256, 0, stream>>>(
            dtbuf, x_act, dbc, A_log, Pbuf, Fbuf);
        scan_combine<<<dim3((BATCH * 16 * D_INNER) / 256), 256, 0, stream>>>(
            Pbuf, Fbuf);
        scan_part2<1><<<dim3(D_INNER / 256, NCHUNK, BATCH), 256, 0, stream>>>(
            dtbuf, x_act, dbc, A_log, Dp, Fbuf, xz + D_INNER, 4096,
            nullptr, yh, yl);

        // 7) out_proj: out = yf @ W_out^T   (64x128 tile -> 256 blocks)
        gemm_mfma2<64, 128, 32, 64><<<dim3(D_MODEL / 128, BT / 64), 256, 0, stream>>>(
            yh, yl, D_INNER, wouth, D_INNER, out, D_MODEL, D_INNER);
    } else {
        // ------------------- fallback: all-fp32 path -----------------------
        float* ws    = (float*)d_ws;
        float* x_in  = ws;
        float* z     = x_in  + (size_t)BT * D_INNER;
        float* x_act = z     + (size_t)BT * D_INNER;
        float* dbc   = x_act + (size_t)BT * D_INNER;
        float* Pbuf  = dbc   + (size_t)BT * 96;
        float* Fbuf  = Pbuf  + (size_t)BATCH * NCHUNK * 16 * D_INNER;
        float* dtbuf = x_in;
        float* yf    = z;

        gemm_nt<64,64,16,4,4,0><<<dim3(D_INNER/64, BT/64), 256, 0, stream>>>(
            x, D_MODEL, W_in, D_MODEL, x_in, D_INNER, D_MODEL, nullptr);
        gemm_nt<64,64,16,4,4,0><<<dim3(D_INNER/64, BT/64), 256, 0, stream>>>(
            x, D_MODEL, W_in + (size_t)D_INNER * D_MODEL, D_MODEL, z, D_INNER, D_MODEL, nullptr);
        conv_silu_kernel<<<dim3((BT * D_INNER) / 256), 256, 0, stream>>>(
            x_in, D_INNER, conv_w, conv_b, x_act);
        gemm_nt<64,32,16,4,4,0><<<dim3(96/32, BT/64), 128, 0, stream>>>(
            x_act, D_INNER, W_x, D_INNER, dbc, 96, D_INNER, nullptr);
        gemm_nt<64,64,16,4,4,1><<<dim3(D_INNER/64, BT/64), 256, 0, stream>>>(
            dbc, 96, W_dt, DT_RANK, dtbuf, D_INNER, DT_RANK, b_dt);
        scan_part1<<<dim3(D_INNER/256, NCHUNK, BATCH), 256, 0, stream>>>(
            dtbuf, x_act, dbc, A_log, Pbuf, Fbuf);
        scan_combine<<<dim3((BATCH * 16 * D_INNER) / 256), 256, 0, stream>>>(
            Pbuf, Fbuf);
        scan_part2<0><<<dim3(D_INNER/256, NCHUNK, BATCH), 256, 0, stream>>>(
            dtbuf, x_act, dbc, A_log, Dp, Fbuf, z, D_INNER, yf, nullptr, nullptr);
        gemm_nt<64,64,16,4,4,0><<<dim3(D_MODEL/64, BT/64), 256, 0, stream>>>(
            yf, D_INNER, W_out, D_INNER, out, D_MODEL, D_INNER, nullptr);
    }
}